// Round 6
// baseline (120.287 us; speedup 1.0000x reference)
//
#include <hip/hip_runtime.h>
#include <hip/hip_bf16.h>
#include <cstddef>

#define NVOX 32768
#define J5 5
#define KB2 1472           // folded K for kv GEMM: 1280 img | 128 pe | 64 const
typedef __hip_bfloat16 bf16;
typedef __attribute__((ext_vector_type(8))) short bf16x8v;
typedef __attribute__((ext_vector_type(4))) float f32x4;

static __device__ __forceinline__ float pe_val(int pos, int c) {
  float dv = expf((float)(c & ~1) * (-0.0719557841560639f));
  float arg = (float)pos * dv;
  return (c & 1) ? cosf(arg) : sinf(arg);
}
static __device__ __forceinline__ short f2b(float f) {
  __hip_bfloat16 h = __float2bfloat16(f);
  return *reinterpret_cast<short*>(&h);
}
static __device__ __forceinline__ float b2f(short s) {
  __hip_bfloat16 h = *reinterpret_cast<__hip_bfloat16*>(&s);
  return __bfloat162float(h);
}
static __device__ __forceinline__ float2 cmul(float2 a, float2 b) {
  return make_float2(a.x * b.x - a.y * b.y, a.x * b.y + a.y * b.x);
}

// block-range boundaries for k_prep sections
#define NB_TABS   24      // tabs: 6144
#define NB_WQPE   64      // Wqb pe-part: 16384
#define NB_WQC    96      // Wqc: 24576
#define NB_WO     32      // Wo: 8192
#define NB_QCB    1       // qcb+obb
#define NB_CVT    1600    // img cvt: 409600 (units of 8)
#define NB_TRI    1536    // tri transpose: 393216
#define NB_FOLDW  1280    // Wkvb2[:, 0:1280] fold: 327680
#define NB_PETAB  128     // pe_tab 256x128 bf16: 32768
#define NB_WIN    128     // Wkvb2[:, 1280:1408] = in_w block: 32768
#define NB_CB     1       // Wkvb2[:, 1408:1472] = cbias/zeros
#define B_TABS   0
#define B_WQPE   (B_TABS + NB_TABS)
#define B_WQC    (B_WQPE + NB_WQPE)
#define B_WO     (B_WQC + NB_WQC)
#define B_QCB    (B_WO + NB_WO)
#define B_CVT    (B_QCB + NB_QCB)
#define B_TRI    (B_CVT + NB_CVT)
#define B_FOLDW  (B_TRI + NB_TRI)
#define B_PETAB  (B_FOLDW + NB_FOLDW)
#define B_WIN    (B_PETAB + NB_PETAB)
#define B_CB     (B_WIN + NB_WIN)
#define NB_TOTAL (B_CB + NB_CB)   // 4890

// ---------- one merged prep kernel ----------
__global__ __launch_bounds__(256) void k_prep(
    const float* __restrict__ img, const float* __restrict__ tp,
    const float* __restrict__ k_w, const float* __restrict__ k_b,
    const float* __restrict__ q_w, const float* __restrict__ q_b,
    const float* __restrict__ v_w, const float* __restrict__ v_b,
    const float* __restrict__ in_w, const float* __restrict__ in_b,
    const float* __restrict__ out_w, const float* __restrict__ out_b,
    const float* __restrict__ proj_w, const float* __restrict__ proj_b,
    float2* __restrict__ tabs, short* __restrict__ Wqb_s, float* __restrict__ Wo,
    float* __restrict__ qcb, float* __restrict__ obb, short* __restrict__ imgb,
    short* __restrict__ tri_tb, short* __restrict__ Wkvb2, short* __restrict__ pe_tab) {
  const int bx = blockIdx.x, t = threadIdx.x;

  if (bx < B_WQPE) {                    // tabs: 3 tables x 32 pos x 64 i
    int idx = bx * 256 + t;
    if (idx < 6144) {
      int tb = idx >> 11, rem = idx & 2047;
      int pos = rem >> 6, i = rem & 63;
      float dv = expf((float)(2 * i) * (-0.0719557841560639f));
      float mult = (tb == 0) ? 1024.0f : (tb == 1) ? 32.0f : 1.0f;
      float ang = (float)pos * mult * dv;
      tabs[idx] = make_float2(cosf(ang), sinf(ang));
    }
  } else if (bx < B_WQC) {              // Wqb pe-part: Wqb[c][192+j] = Wq[c][j]
    int e = (bx - B_WQPE) * 256 + t;    // < 16384
    int c = e >> 7, j = e & 127;
    Wqb_s[(size_t)c * 320 + 192 + j] = f2b(in_w[(size_t)c * 128 + j]);
  } else if (bx < B_WO) {               // Wqc: Wqb[c][k] = Wq[c,:] . q_w[:,k]
    int e = (bx - B_WQC) * 256 + t;     // < 24576
    int c = e / 192, k = e % 192;
    const float* ir = in_w + (size_t)c * 128;
    float acc = 0.f;
    for (int j = 0; j < 128; j++) acc = fmaf(ir[j], q_w[(size_t)j * 192 + k], acc);
    Wqb_s[(size_t)c * 320 + k] = f2b(acc);
  } else if (bx < B_QCB) {              // Wo[o][c] = proj_w[o,:] . out_w[:,c]
    int e = (bx - B_WO) * 256 + t;      // < 8192
    int o = e >> 7, c = e & 127;
    const float* pr = proj_w + (size_t)o * 128;
    float acc = 0.f;
    for (int j = 0; j < 128; j++) acc = fmaf(pr[j], out_w[(size_t)j * 128 + c], acc);
    Wo[e] = acc;
  } else if (bx < B_CVT) {              // qcb / obb
    if (t < 128) {
      float acc = in_b[t];
      const float* ir = in_w + (size_t)t * 128;
      for (int j = 0; j < 128; j++) acc = fmaf(ir[j], q_b[j], acc);
      qcb[t] = acc;
    }
    if (t < 64) {
      float acc = proj_b[t];
      const float* pr = proj_w + (size_t)t * 128;
      for (int j = 0; j < 128; j++) acc = fmaf(pr[j], out_b[j], acc);
      obb[t] = acc;
    }
  } else if (bx < B_TRI) {              // img -> bf16 (skip cls)
    int e8 = (bx - B_CVT) * 256 + t;    // < 409600
    int row = e8 / 160, k8 = e8 % 160;
    int bj = row >> 8, p = row & 255;
    const float* src = img + ((size_t)(bj * 257 + 1 + p)) * 1280 + k8 * 8;
    float4 a = *(const float4*)src;
    float4 b = *(const float4*)(src + 4);
    bf16x8v v;
    v[0] = f2b(a.x); v[1] = f2b(a.y); v[2] = f2b(a.z); v[3] = f2b(a.w);
    v[4] = f2b(b.x); v[5] = f2b(b.y); v[6] = f2b(b.z); v[7] = f2b(b.w);
    *reinterpret_cast<bf16x8v*>(imgb + (size_t)row * 1280 + k8 * 8) = v;
  } else if (bx < B_FOLDW) {            // triplane transpose -> bf16
    int idx = (bx - B_TRI) * 256 + t;   // < 393216
    int cc   = idx & 63;
    int rem  = idx >> 6;
    int cell = rem & 1023;
    int segb = rem >> 10;
    int seg = segb % 3, b = segb / 3;
    int i = cell >> 5, j = cell & 31;
    tri_tb[idx] = f2b(tp[(((size_t)(b * 64 + cc)) * 96 + seg * 32 + i) * 32 + j]);
  } else if (bx < B_PETAB) {            // Wkvb2[c][0:1280] = Wk/Wv[c,:] . {k_w,v_w}[:,k]
    int u = (bx - B_FOLDW) * 256 + t;   // < 327680 ; c uniform per block (1280 = 5*256)
    int c = u / 1280, k = u % 1280;
    const float* w = (c < 128) ? k_w : v_w;
    const float* ir = in_w + (size_t)(128 + c) * 128;
    float acc = 0.f;
    for (int j = 0; j < 128; j++) acc = fmaf(ir[j], w[(size_t)j * 1280 + k], acc);
    Wkvb2[(size_t)c * KB2 + k] = f2b(acc);
  } else if (bx < B_WIN) {              // pe_tab[p][c] bf16
    int e = (bx - B_PETAB) * 256 + t;   // < 32768
    int p = e >> 7, c = e & 127;
    pe_tab[e] = f2b(pe_val(p, c));
  } else if (bx < B_CB) {               // Wkvb2[c][1280:1408] = in_w[128+c][j]
    int e = (bx - B_WIN) * 256 + t;     // < 32768
    int c = e >> 7, j = e & 127;
    Wkvb2[(size_t)c * KB2 + 1280 + j] = f2b(in_w[(size_t)(128 + c) * 128 + j]);
  } else {                              // Wkvb2[c][1408:1472]: cbias at 1408, zeros after
    int c = t;                          // 256 threads
    int which = c >> 7;
    const float* bias = which ? v_b : k_b;
    const float* ir = in_w + (size_t)(128 + c) * 128;
    float acc = in_b[128 + c];
    for (int j = 0; j < 128; j++) acc = fmaf(bias[j], ir[j], acc);
    short* row = Wkvb2 + (size_t)c * KB2 + 1408;
    row[0] = f2b(acc);
    for (int k = 1; k < 64; k++) row[k] = 0;
  }
}

// ---------- MFMA GEMM: k2v2[2560][256] = [img|pe|1] @ Wkvb2^T ; tile 32x64 ----------
__global__ __launch_bounds__(256) void k_gemm_kv(
    const short* __restrict__ imgb, const short* __restrict__ Wkvb2,
    const short* __restrict__ pe_tab, short* __restrict__ k2b, short* __restrict__ v2b) {
  __shared__ __align__(16) short A_lds[32 * 64];
  __shared__ __align__(16) short B_lds[64 * 64];
  const int m0 = blockIdx.x * 32;
  const int nb0 = blockIdx.y * 64;
  const int t = threadIdx.x;
  const int lane = t & 63, w = t >> 6;
  const int wm = w & 1, wn = w >> 1;
  f32x4 acc[2];
  acc[0] = (f32x4){0.f, 0.f, 0.f, 0.f};
  acc[1] = (f32x4){0.f, 0.f, 0.f, 0.f};

  for (int ct = 0; ct < 23; ct++) {
    __syncthreads();
    {   // A: 32 rows x 64 k = 2048 shorts, 1 int4/thread
      int r = t >> 3, g = t & 7;
      bf16x8v v;
      if (ct < 20) {
        v = *reinterpret_cast<const bf16x8v*>(imgb + (size_t)(m0 + r) * 1280 + ct * 64 + g * 8);
      } else if (ct < 22) {
        int p = (m0 + r) & 255;
        v = *reinterpret_cast<const bf16x8v*>(pe_tab + (size_t)p * 128 + (ct - 20) * 64 + g * 8);
      } else {
        v = (bf16x8v){0, 0, 0, 0, 0, 0, 0, 0};
        if (g == 0) v[0] = (short)0x3F80;   // bf16 1.0 at k-offset 1408
      }
      *reinterpret_cast<bf16x8v*>(&A_lds[(r * 8 + (g ^ (r & 7))) * 8]) = v;
    }
    {   // B: 64 c-rows x 64 k = 4096 shorts, 2 int4/thread
#pragma unroll
      for (int it = 0; it < 2; it++) {
        int u = it * 256 + t;
        int r2 = u >> 3, g = u & 7;
        const int4 src = *reinterpret_cast<const int4*>(
            Wkvb2 + (size_t)(nb0 + r2) * KB2 + ct * 64 + g * 8);
        *reinterpret_cast<int4*>(&B_lds[(r2 * 8 + (g ^ (r2 & 7))) * 8]) = src;
      }
    }
    __syncthreads();
#pragma unroll
    for (int ks = 0; ks < 2; ks++) {
      int kb = ks * 4 + (lane >> 4);
      int arow = wm * 16 + (lane & 15);
      bf16x8v a = *reinterpret_cast<const bf16x8v*>(&A_lds[(arow * 8 + (kb ^ (arow & 7))) * 8]);
#pragma unroll
      for (int f = 0; f < 2; f++) {
        int bcol = wn * 32 + f * 16 + (lane & 15);
        bf16x8v bb = *reinterpret_cast<const bf16x8v*>(&B_lds[(bcol * 8 + (kb ^ (bcol & 7))) * 8]);
        acc[f] = __builtin_amdgcn_mfma_f32_16x16x32_bf16(a, bb, acc[f], 0, 0, 0);
      }
    }
  }
#pragma unroll
  for (int f = 0; f < 2; f++) {
#pragma unroll
    for (int reg = 0; reg < 4; reg++) {
      int grow = m0 + wm * 16 + (lane >> 4) * 4 + reg;
      int gcol = nb0 + wn * 32 + f * 16 + (lane & 15);
      int which = gcol >> 7, c = gcol & 127;
      short* dst = which ? v2b : k2b;
      dst[(size_t)grow * 128 + c] = f2b(acc[f][reg]);
    }
  }
}

// ---------- fused main (32 vox/block): MFMA q-GEMM (B from global) + proj + sample + attention ----------
__global__ __launch_bounds__(256) void k_main(
    const short* __restrict__ tri_tb, const short* __restrict__ Wqb_s,
    const float* __restrict__ qcb, const float2* __restrict__ tabs,
    const short* __restrict__ k2b, const short* __restrict__ v2b,
    const float* __restrict__ proj, bf16* __restrict__ obuf) {
  __shared__ __align__(16) short A_lds[32 * 64];
  __shared__ __align__(16) short qh_lds[32 * 128];
  __shared__ __align__(16) ushort sIr[160][4];
  __shared__ __align__(16) float sW4[160][4];
  __shared__ __align__(16) float lg[160 * 8];
  const int b = blockIdx.y;
  const int n0 = blockIdx.x * 32;
  const int t = threadIdx.x;
  const int lane = t & 63, w = t >> 6;
  const int xq = n0 >> 10, yq = (n0 >> 5) & 31;   // uniform; z spans 0..31
  const float2* tabX = tabs;
  const float2* tabY = tabs + 2048;
  const float2* tabZ = tabs + 4096;

  // phase C: projection + bilinear taps (t < 160)
  if (t < 160) {
    int r = t / J5, j = t % J5;
    int n = n0 + r;
    int x = n >> 10, y = (n >> 5) & 31, z = n & 31;
    const float SC = (float)(1.0 + 0.1 + 1e-05);
    float fx = ((float)x / 31.0f - 0.5f) * 2.0f * SC;
    float fy = ((float)y / 31.0f - 0.5f) * 2.0f * SC;
    float fz = ((float)z / 31.0f - 0.5f) * 2.0f * SC;
    const float* P = proj + (size_t)(b * J5 + j) * 16;
    float pc0 = fmaf(fx, P[0], fmaf(fy, P[1], fmaf(fz, P[2],  P[3])));
    float pc1 = fmaf(fx, P[4], fmaf(fy, P[5], fmaf(fz, P[6],  P[7])));
    float pc2 = fmaf(fx, P[8], fmaf(fy, P[9], fmaf(fz, P[10], P[11])));
    float px = pc0 / pc2, py = pc1 / pc2;
    float gx = fminf(fmaxf((px / 223.0f - 0.5f) * 2.0f, -1.0f), 1.0f);
    float gy = fminf(fmaxf((py / 223.0f - 0.5f) * 2.0f, -1.0f), 1.0f);
    float ux = (gx + 1.0f) * 0.5f * 15.0f;
    float uy = (gy + 1.0f) * 0.5f * 15.0f;
    float fx0 = floorf(ux), fy0 = floorf(uy);
    int x0 = (int)fx0, y0 = (int)fy0;
    float wx = ux - fx0, wy = uy - fy0;
    int x1 = min(x0 + 1, 15), y1 = min(y0 + 1, 15);
    x0 = min(max(x0, 0), 15); y0 = min(max(y0, 0), 15);
    int rowb = (b * J5 + j) * 256;
    sIr[t][0] = (ushort)(rowb + y0 * 16 + x0);
    sIr[t][1] = (ushort)(rowb + y0 * 16 + x1);
    sIr[t][2] = (ushort)(rowb + y1 * 16 + x0);
    sIr[t][3] = (ushort)(rowb + y1 * 16 + x1);
    sW4[t][0] = (1.f - wx) * (1.f - wy);
    sW4[t][1] = wx * (1.f - wy);
    sW4[t][2] = (1.f - wx) * wy;
    sW4[t][3] = wx * wy;
  }

  // phase B: qh = [tri | pe] @ Wqb^T + qcb via MFMA; A staged in LDS, B straight from L2
  f32x4 acc[2][2];
#pragma unroll
  for (int m = 0; m < 2; m++)
#pragma unroll
    for (int f = 0; f < 2; f++) acc[m][f] = (f32x4){0.f, 0.f, 0.f, 0.f};

  for (int ct = 0; ct < 5; ct++) {
    __syncthreads();
    {   // stage A chunk: 32 rows x 64 cols (256 threads, 1 int4 each)
      int r = t >> 3, g = t & 7;
      if (ct < 3) {
        int n = n0 + r;
        int x = n >> 10, y = (n >> 5) & 31, z = n & 31;
        int cell = (ct == 0) ? (z * 32 + x) : (ct == 1) ? (y * 32 + x) : (z * 32 + y);
        const int4 src = *reinterpret_cast<const int4*>(
            tri_tb + ((size_t)(b * 3 + ct) * 1024 + cell) * 64 + g * 8);
        *reinterpret_cast<int4*>(&A_lds[(r * 8 + (g ^ (r & 7))) * 8]) = src;
      } else {
        int i0 = (ct - 3) * 32 + g * 4;
        bf16x8v v;
#pragma unroll
        for (int q = 0; q < 4; q++) {
          int i = i0 + q;
          float2 exy = cmul(tabX[xq * 64 + i], tabY[yq * 64 + i]);
          float2 e = cmul(exy, tabZ[r * 64 + i]);   // z == r (32-aligned block)
          v[q * 2]     = f2b(e.y);   // sin
          v[q * 2 + 1] = f2b(e.x);   // cos
        }
        *reinterpret_cast<bf16x8v*>(&A_lds[(r * 8 + (g ^ (r & 7))) * 8]) = v;
      }
    }
    __syncthreads();
#pragma unroll
    for (int ks = 0; ks < 2; ks++) {
      int kb = ks * 4 + (lane >> 4);
      bf16x8v a[2], bb[2];
#pragma unroll
      for (int f = 0; f < 2; f++) {
        int col = w * 32 + f * 16 + (lane & 15);
        bb[f] = *reinterpret_cast<const bf16x8v*>(Wqb_s + (size_t)col * 320 + ct * 64 + kb * 8);
      }
#pragma unroll
      for (int m = 0; m < 2; m++) {
        int row = m * 16 + (lane & 15);
        a[m] = *reinterpret_cast<const bf16x8v*>(&A_lds[(row * 8 + (kb ^ (row & 7))) * 8]);
      }
#pragma unroll
      for (int m = 0; m < 2; m++)
#pragma unroll
        for (int f = 0; f < 2; f++)
          acc[m][f] = __builtin_amdgcn_mfma_f32_16x16x32_bf16(a[m], bb[f], acc[m][f], 0, 0, 0);
    }
  }
  // epilogue: qh_lds = acc + qcb (bf16)
#pragma unroll
  for (int m = 0; m < 2; m++)
#pragma unroll
    for (int f = 0; f < 2; f++)
#pragma unroll
      for (int reg = 0; reg < 4; reg++) {
        int row = m * 16 + (lane >> 4) * 4 + reg;
        int col = w * 32 + f * 16 + (lane & 15);
        qh_lds[row * 128 + col] = f2b(acc[m][f][reg] + qcb[col]);
      }
  __syncthreads();

  // phase D: logits — octet-per-thread, bf16x8 loads, single shfl
  {
    const int oct = t & 15, rjIdx = t >> 4;
    const int c0 = oct * 8;
#pragma unroll
    for (int it = 0; it < 10; it++) {
      int rj = rjIdx + it * 16;
      int r = rj / J5;
      ushort4 I4 = *reinterpret_cast<const ushort4*>(sIr[rj]);
      float4 W4 = *reinterpret_cast<const float4*>(sW4[rj]);
      bf16x8v t0 = *reinterpret_cast<const bf16x8v*>(k2b + (size_t)I4.x * 128 + c0);
      bf16x8v t1 = *reinterpret_cast<const bf16x8v*>(k2b + (size_t)I4.y * 128 + c0);
      bf16x8v t2 = *reinterpret_cast<const bf16x8v*>(k2b + (size_t)I4.z * 128 + c0);
      bf16x8v t3 = *reinterpret_cast<const bf16x8v*>(k2b + (size_t)I4.w * 128 + c0);
      bf16x8v q8 = *reinterpret_cast<const bf16x8v*>(&qh_lds[r * 128 + c0]);
      float pv = 0.f;
#pragma unroll
      for (int e = 0; e < 8; e++) {
        float kh = fmaf(W4.x, b2f(t0[e]), fmaf(W4.y, b2f(t1[e]),
                   fmaf(W4.z, b2f(t2[e]), W4.w * b2f(t3[e]))));
        pv = fmaf(b2f(q8[e]), kh, pv);
      }
      pv += __shfl_xor(pv, 1);
      if (!(oct & 1)) lg[rj * 8 + (oct >> 1)] = pv * 0.25f;
    }
  }
  __syncthreads();

  // phase E: softmax over j per (r,h): 32*8 = 256 threads
  {
    int r = t >> 3, h = t & 7;
    float l[J5];
    float m = -1e30f;
#pragma unroll
    for (int j = 0; j < J5; j++) { l[j] = lg[(r * J5 + j) * 8 + h]; m = fmaxf(m, l[j]); }
    float sden = 0.f;
#pragma unroll
    for (int j = 0; j < J5; j++) { l[j] = expf(l[j] - m); sden += l[j]; }
    float inv = 1.0f / sden;
#pragma unroll
    for (int j = 0; j < J5; j++) lg[(r * J5 + j) * 8 + h] = l[j] * inv;
  }
  __syncthreads();

  // phase F: output — octet-per-thread accumulation, 2 rows/thread
  {
    const int oct = t & 15;
    const int c0 = oct * 8;
#pragma unroll
    for (int it = 0; it < 2; it++) {
      int r = (t >> 4) + it * 16;
      float o8[8] = {0.f, 0.f, 0.f, 0.f, 0.f, 0.f, 0.f, 0.f};
#pragma unroll
      for (int j = 0; j < J5; j++) {
        int rj = r * J5 + j;
        float aw = lg[rj * 8 + (oct >> 1)];
        ushort4 I4 = *reinterpret_cast<const ushort4*>(sIr[rj]);
        float4 W4 = *reinterpret_cast<const float4*>(sW4[rj]);
        float w0 = aw * W4.x, w1 = aw * W4.y, w2 = aw * W4.z, w3 = aw * W4.w;
        bf16x8v t0 = *reinterpret_cast<const bf16x8v*>(v2b + (size_t)I4.x * 128 + c0);
        bf16x8v t1 = *reinterpret_cast<const bf16x8v*>(v2b + (size_t)I4.y * 128 + c0);
        bf16x8v t2 = *reinterpret_cast<const bf16x8v*>(v2b + (size_t)I4.z * 128 + c0);
        bf16x8v t3 = *reinterpret_cast<const bf16x8v*>(v2b + (size_t)I4.w * 128 + c0);
#pragma unroll
        for (int e = 0; e < 8; e++) {
          o8[e] = fmaf(w0, b2f(t0[e]), o8[e]);
          o8[e] = fmaf(w1, b2f(t1[e]), o8[e]);
          o8[e] = fmaf(w2, b2f(t2[e]), o8[e]);
          o8[e] = fmaf(w3, b2f(t3[e]), o8[e]);
        }
      }
      bf16x8v out;
#pragma unroll
      for (int e = 0; e < 8; e++) out[e] = f2b(o8[e]);
      *reinterpret_cast<bf16x8v*>((short*)obuf + ((size_t)b * NVOX + n0 + r) * 128 + c0) = out;
    }
  }
}

// ---------- full-volume plane reductions (bf16x8 loads, 8 cells/block) ----------
__global__ __launch_bounds__(128) void k_reduce(const bf16* __restrict__ obuf,
                                                float* __restrict__ pacc) {
  int blk = blockIdx.x;          // 0..383 ; 8 cells/block
  int b = blockIdx.y;
  int t = threadIdx.x;
  int oct = t & 15, sub = t >> 4;
  int c0 = oct * 8;
  int cell = blk * 8 + sub;      // 0..3071
  const short* ob = (const short*)obuf + (size_t)b * NVOX * 128;
  float a8[8] = {0.f, 0.f, 0.f, 0.f, 0.f, 0.f, 0.f, 0.f};
  size_t prow;
  if (cell < 1024) {             // xz: row=z, col=x ; sum over y
    int z = cell >> 5, x = cell & 31;
    for (int y = 0; y < 32; y++) {
      bf16x8v u = *reinterpret_cast<const bf16x8v*>(ob + ((size_t)(x * 1024 + y * 32 + z) * 128 + c0));
#pragma unroll
      for (int e = 0; e < 8; e++) a8[e] += b2f(u[e]);
    }
    prow = ((size_t)(b * 96 + z) * 32 + x) * 128 + c0;
  } else if (cell < 2048) {      // xy: row=y, col=x ; sum over z
    int e2 = cell - 1024;
    int y = e2 >> 5, x = e2 & 31;
    for (int z = 0; z < 32; z++) {
      bf16x8v u = *reinterpret_cast<const bf16x8v*>(ob + ((size_t)(x * 1024 + y * 32 + z) * 128 + c0));
#pragma unroll
      for (int e = 0; e < 8; e++) a8[e] += b2f(u[e]);
    }
    prow = ((size_t)(b * 96 + 32 + y) * 32 + x) * 128 + c0;
  } else {                       // yz: row=z, col=y ; sum over x
    int e2 = cell - 2048;
    int z = e2 >> 5, y = e2 & 31;
    for (int x = 0; x < 32; x++) {
      bf16x8v u = *reinterpret_cast<const bf16x8v*>(ob + ((size_t)(x * 1024 + y * 32 + z) * 128 + c0));
#pragma unroll
      for (int e = 0; e < 8; e++) a8[e] += b2f(u[e]);
    }
    prow = ((size_t)(b * 96 + 64 + z) * 32 + y) * 128 + c0;
  }
  *(float4*)(&pacc[prow])     = (float4){a8[0], a8[1], a8[2], a8[3]};
  *(float4*)(&pacc[prow + 4]) = (float4){a8[4], a8[5], a8[6], a8[7]};
}

// ---------- final projection ----------
__global__ __launch_bounds__(128) void k_final(
    const float* __restrict__ pacc, const float* __restrict__ Wo,
    const float* __restrict__ obb, float* __restrict__ outp) {
  int bp = blockIdx.x;
  int b = bp / 96, prow = bp % 96;
  int obase = blockIdx.y * 16;
  __shared__ __align__(16) float lds[32 * 129];
  for (int idx = threadIdx.x; idx < 4096; idx += 128) {
    int col = idx >> 7, k = idx & 127;
    lds[col * 129 + k] = pacc[(size_t)bp * 32 * 128 + idx] * (1.0f / 32.0f);
  }
  __syncthreads();
  for (int e = threadIdx.x; e < 16 * 32; e += 128) {
    int o = obase + (e >> 5), col = e & 31;
    float val = obb[o];
    const float* wr = Wo + (size_t)o * 128;
    const float* lr = lds + col * 129;
    for (int k = 0; k < 128; k++) val = fmaf(wr[k], lr[k], val);
    outp[((size_t)(b * 64 + o) * 96 + prow) * 32 + col] = val;
  }
}

extern "C" void kernel_launch(void* const* d_in, const int* in_sizes, int n_in,
                              void* d_out, int out_size, void* d_ws, size_t ws_size,
                              hipStream_t stream) {
  const float* tp     = (const float*)d_in[0];
  const float* img    = (const float*)d_in[1];
  const float* proj   = (const float*)d_in[2];
  const float* k_w    = (const float*)d_in[4];
  const float* k_b    = (const float*)d_in[5];
  const float* q_w    = (const float*)d_in[6];
  const float* q_b    = (const float*)d_in[7];
  const float* v_w    = (const float*)d_in[8];
  const float* v_b    = (const float*)d_in[9];
  const float* in_w   = (const float*)d_in[10];
  const float* in_b   = (const float*)d_in[11];
  const float* out_w  = (const float*)d_in[12];
  const float* out_b  = (const float*)d_in[13];
  const float* proj_w = (const float*)d_in[14];
  const float* proj_b = (const float*)d_in[15];
  const int B = 2;

  float* ws = (float*)d_ws;
  size_t off = 0;
  short*  tri_tb = (short*)(ws + off);  off += 196608;   // 2*3*1024*64 bf16
  short*  Wkvb2  = (short*)(ws + off);  off += 188416;   // 256*1472 bf16
  short*  Wqb_s  = (short*)(ws + off);  off += 20480;    // 128*320 bf16
  short*  pe_tab = (short*)(ws + off);  off += 16384;    // 256*128 bf16
  float2* tabs   = (float2*)(ws + off); off += 12288;    // 3*32*64 cplx
  float*  qcb    = ws + off;            off += 128;
  float*  Wo     = ws + off;            off += 8192;
  float*  obb    = ws + off;            off += 64;
  short*  k2b    = (short*)(ws + off);  off += 163840;   // 2560*128 bf16
  short*  v2b    = (short*)(ws + off);  off += 163840;
  float*  pacc   = ws + off;            off += 786432;   // 2*96*32*128
  float*  zone   = ws + off;            off += 4194304;  // max(imgb 1.6M, obuf 4.2M slots)
  short*  imgb   = (short*)zone;                         // 2560*1280 bf16 (early)
  bf16*   obuf   = (bf16*)zone;                          // 2*32768*128 bf16 (late)
  if (ws_size < off * sizeof(float)) return;  // ~23 MB needed; clean fail if short

  k_prep<<<dim3(NB_TOTAL), dim3(256), 0, stream>>>(
      img, tp, k_w, k_b, q_w, q_b, v_w, v_b, in_w, in_b, out_w, out_b, proj_w, proj_b,
      tabs, Wqb_s, Wo, qcb, obb, imgb, tri_tb, Wkvb2, pe_tab);
  k_gemm_kv<<<dim3(80, 4), dim3(256), 0, stream>>>(imgb, Wkvb2, pe_tab, k2b, v2b);
  k_main<<<dim3(NVOX / 32, B), dim3(256), 0, stream>>>(
      tri_tb, Wqb_s, qcb, tabs, k2b, v2b, proj, obuf);
  k_reduce<<<dim3(384, B), dim3(128), 0, stream>>>(obuf, pacc);
  k_final<<<dim3(B * 96, 4), dim3(128), 0, stream>>>(pacc, Wo, obb, (float*)d_out);
}

// Round 7
// 119.763 us; speedup vs baseline: 1.0044x; 1.0044x over previous
//
#include <hip/hip_runtime.h>
#include <hip/hip_bf16.h>
#include <cstddef>

#define NVOX 32768
#define J5 5
#define KB2 1472           // folded K for kv GEMM: 1280 img | 128 pe | 64 const
typedef __hip_bfloat16 bf16;
typedef __attribute__((ext_vector_type(8))) short bf16x8v;
typedef __attribute__((ext_vector_type(4))) float f32x4;

static __device__ __forceinline__ float pe_val(int pos, int c) {
  float dv = expf((float)(c & ~1) * (-0.0719557841560639f));
  float arg = (float)pos * dv;
  return (c & 1) ? cosf(arg) : sinf(arg);
}
static __device__ __forceinline__ short f2b(float f) {
  __hip_bfloat16 h = __float2bfloat16(f);
  return *reinterpret_cast<short*>(&h);
}
static __device__ __forceinline__ float b2f(short s) {
  __hip_bfloat16 h = *reinterpret_cast<__hip_bfloat16*>(&s);
  return __bfloat162float(h);
}
static __device__ __forceinline__ float2 cmul(float2 a, float2 b) {
  return make_float2(a.x * b.x - a.y * b.y, a.x * b.y + a.y * b.x);
}

// block-range boundaries for k_prep sections
#define NB_TABS   24
#define NB_WQPE   64
#define NB_WQC    96
#define NB_WO     32
#define NB_QCB    1
#define NB_CVT    1600
#define NB_TRI    1536
#define NB_FOLDW  1280
#define NB_PETAB  128
#define NB_WIN    128
#define NB_CB     1
#define B_TABS   0
#define B_WQPE   (B_TABS + NB_TABS)
#define B_WQC    (B_WQPE + NB_WQPE)
#define B_WO     (B_WQC + NB_WQC)
#define B_QCB    (B_WO + NB_WO)
#define B_CVT    (B_QCB + NB_QCB)
#define B_TRI    (B_CVT + NB_CVT)
#define B_FOLDW  (B_TRI + NB_TRI)
#define B_PETAB  (B_FOLDW + NB_FOLDW)
#define B_WIN    (B_PETAB + NB_PETAB)
#define B_CB     (B_WIN + NB_WIN)
#define NB_TOTAL (B_CB + NB_CB)

// ---------- one merged prep kernel ----------
__global__ __launch_bounds__(256) void k_prep(
    const float* __restrict__ img, const float* __restrict__ tp,
    const float* __restrict__ k_w, const float* __restrict__ k_b,
    const float* __restrict__ q_w, const float* __restrict__ q_b,
    const float* __restrict__ v_w, const float* __restrict__ v_b,
    const float* __restrict__ in_w, const float* __restrict__ in_b,
    const float* __restrict__ out_w, const float* __restrict__ out_b,
    const float* __restrict__ proj_w, const float* __restrict__ proj_b,
    float2* __restrict__ tabs, short* __restrict__ Wqb_s, float* __restrict__ Wo,
    float* __restrict__ qcb, float* __restrict__ obb, short* __restrict__ imgb,
    short* __restrict__ tri_tb, short* __restrict__ Wkvb2, short* __restrict__ pe_tab) {
  const int bx = blockIdx.x, t = threadIdx.x;

  if (bx < B_WQPE) {
    int idx = bx * 256 + t;
    if (idx < 6144) {
      int tb = idx >> 11, rem = idx & 2047;
      int pos = rem >> 6, i = rem & 63;
      float dv = expf((float)(2 * i) * (-0.0719557841560639f));
      float mult = (tb == 0) ? 1024.0f : (tb == 1) ? 32.0f : 1.0f;
      float ang = (float)pos * mult * dv;
      tabs[idx] = make_float2(cosf(ang), sinf(ang));
    }
  } else if (bx < B_WQC) {
    int e = (bx - B_WQPE) * 256 + t;
    int c = e >> 7, j = e & 127;
    Wqb_s[(size_t)c * 320 + 192 + j] = f2b(in_w[(size_t)c * 128 + j]);
  } else if (bx < B_WO) {
    int e = (bx - B_WQC) * 256 + t;
    int c = e / 192, k = e % 192;
    const float* ir = in_w + (size_t)c * 128;
    float acc = 0.f;
    for (int j = 0; j < 128; j++) acc = fmaf(ir[j], q_w[(size_t)j * 192 + k], acc);
    Wqb_s[(size_t)c * 320 + k] = f2b(acc);
  } else if (bx < B_QCB) {
    int e = (bx - B_WO) * 256 + t;
    int o = e >> 7, c = e & 127;
    const float* pr = proj_w + (size_t)o * 128;
    float acc = 0.f;
    for (int j = 0; j < 128; j++) acc = fmaf(pr[j], out_w[(size_t)j * 128 + c], acc);
    Wo[e] = acc;
  } else if (bx < B_CVT) {
    if (t < 128) {
      float acc = in_b[t];
      const float* ir = in_w + (size_t)t * 128;
      for (int j = 0; j < 128; j++) acc = fmaf(ir[j], q_b[j], acc);
      qcb[t] = acc;
    }
    if (t < 64) {
      float acc = proj_b[t];
      const float* pr = proj_w + (size_t)t * 128;
      for (int j = 0; j < 128; j++) acc = fmaf(pr[j], out_b[j], acc);
      obb[t] = acc;
    }
  } else if (bx < B_TRI) {
    int e8 = (bx - B_CVT) * 256 + t;
    int row = e8 / 160, k8 = e8 % 160;
    int bj = row >> 8, p = row & 255;
    const float* src = img + ((size_t)(bj * 257 + 1 + p)) * 1280 + k8 * 8;
    float4 a = *(const float4*)src;
    float4 b = *(const float4*)(src + 4);
    bf16x8v v;
    v[0] = f2b(a.x); v[1] = f2b(a.y); v[2] = f2b(a.z); v[3] = f2b(a.w);
    v[4] = f2b(b.x); v[5] = f2b(b.y); v[6] = f2b(b.z); v[7] = f2b(b.w);
    *reinterpret_cast<bf16x8v*>(imgb + (size_t)row * 1280 + k8 * 8) = v;
  } else if (bx < B_FOLDW) {
    int idx = (bx - B_TRI) * 256 + t;
    int cc   = idx & 63;
    int rem  = idx >> 6;
    int cell = rem & 1023;
    int segb = rem >> 10;
    int seg = segb % 3, b = segb / 3;
    int i = cell >> 5, j = cell & 31;
    tri_tb[idx] = f2b(tp[(((size_t)(b * 64 + cc)) * 96 + seg * 32 + i) * 32 + j]);
  } else if (bx < B_PETAB) {
    int u = (bx - B_FOLDW) * 256 + t;
    int c = u / 1280, k = u % 1280;
    const float* w = (c < 128) ? k_w : v_w;
    const float* ir = in_w + (size_t)(128 + c) * 128;
    float acc = 0.f;
    for (int j = 0; j < 128; j++) acc = fmaf(ir[j], w[(size_t)j * 1280 + k], acc);
    Wkvb2[(size_t)c * KB2 + k] = f2b(acc);
  } else if (bx < B_WIN) {
    int e = (bx - B_PETAB) * 256 + t;
    int p = e >> 7, c = e & 127;
    pe_tab[e] = f2b(pe_val(p, c));
  } else if (bx < B_CB) {
    int e = (bx - B_WIN) * 256 + t;
    int c = e >> 7, j = e & 127;
    Wkvb2[(size_t)c * KB2 + 1280 + j] = f2b(in_w[(size_t)(128 + c) * 128 + j]);
  } else {
    int c = t;
    int which = c >> 7;
    const float* bias = which ? v_b : k_b;
    const float* ir = in_w + (size_t)(128 + c) * 128;
    float acc = in_b[128 + c];
    for (int j = 0; j < 128; j++) acc = fmaf(bias[j], ir[j], acc);
    short* row = Wkvb2 + (size_t)c * KB2 + 1408;
    row[0] = f2b(acc);
    for (int k = 1; k < 64; k++) row[k] = 0;
  }
}

// ---------- MFMA GEMM: k2v2[2560][256] = [img|pe|1] @ Wkvb2^T ; tile 32x64 ----------
__global__ __launch_bounds__(256) void k_gemm_kv(
    const short* __restrict__ imgb, const short* __restrict__ Wkvb2,
    const short* __restrict__ pe_tab, short* __restrict__ k2b, short* __restrict__ v2b) {
  __shared__ __align__(16) short A_lds[32 * 64];
  __shared__ __align__(16) short B_lds[64 * 64];
  const int m0 = blockIdx.x * 32;
  const int nb0 = blockIdx.y * 64;
  const int t = threadIdx.x;
  const int lane = t & 63, w = t >> 6;
  const int wm = w & 1, wn = w >> 1;
  f32x4 acc[2];
  acc[0] = (f32x4){0.f, 0.f, 0.f, 0.f};
  acc[1] = (f32x4){0.f, 0.f, 0.f, 0.f};

  for (int ct = 0; ct < 23; ct++) {
    __syncthreads();
    {
      int r = t >> 3, g = t & 7;
      bf16x8v v;
      if (ct < 20) {
        v = *reinterpret_cast<const bf16x8v*>(imgb + (size_t)(m0 + r) * 1280 + ct * 64 + g * 8);
      } else if (ct < 22) {
        int p = (m0 + r) & 255;
        v = *reinterpret_cast<const bf16x8v*>(pe_tab + (size_t)p * 128 + (ct - 20) * 64 + g * 8);
      } else {
        v = (bf16x8v){0, 0, 0, 0, 0, 0, 0, 0};
        if (g == 0) v[0] = (short)0x3F80;
      }
      *reinterpret_cast<bf16x8v*>(&A_lds[(r * 8 + (g ^ (r & 7))) * 8]) = v;
    }
    {
#pragma unroll
      for (int it = 0; it < 2; it++) {
        int u = it * 256 + t;
        int r2 = u >> 3, g = u & 7;
        const int4 src = *reinterpret_cast<const int4*>(
            Wkvb2 + (size_t)(nb0 + r2) * KB2 + ct * 64 + g * 8);
        *reinterpret_cast<int4*>(&B_lds[(r2 * 8 + (g ^ (r2 & 7))) * 8]) = src;
      }
    }
    __syncthreads();
#pragma unroll
    for (int ks = 0; ks < 2; ks++) {
      int kb = ks * 4 + (lane >> 4);
      int arow = wm * 16 + (lane & 15);
      bf16x8v a = *reinterpret_cast<const bf16x8v*>(&A_lds[(arow * 8 + (kb ^ (arow & 7))) * 8]);
#pragma unroll
      for (int f = 0; f < 2; f++) {
        int bcol = wn * 32 + f * 16 + (lane & 15);
        bf16x8v bb = *reinterpret_cast<const bf16x8v*>(&B_lds[(bcol * 8 + (kb ^ (bcol & 7))) * 8]);
        acc[f] = __builtin_amdgcn_mfma_f32_16x16x32_bf16(a, bb, acc[f], 0, 0, 0);
      }
    }
  }
#pragma unroll
  for (int f = 0; f < 2; f++) {
#pragma unroll
    for (int reg = 0; reg < 4; reg++) {
      int grow = m0 + wm * 16 + (lane >> 4) * 4 + reg;
      int gcol = nb0 + wn * 32 + f * 16 + (lane & 15);
      int which = gcol >> 7, c = gcol & 127;
      short* dst = which ? v2b : k2b;
      dst[(size_t)grow * 128 + c] = f2b(acc[f][reg]);
    }
  }
}

// ---------- qh GEMM (standalone MFMA): qh = [tri|pe] @ Wqb^T + qcb, bf16 out ----------
__global__ __launch_bounds__(256) void k_qh(
    const short* __restrict__ tri_tb, const short* __restrict__ Wqb_s,
    const float* __restrict__ qcb, const float2* __restrict__ tabs,
    short* __restrict__ qh_g) {
  __shared__ __align__(16) short A_lds[32 * 64];
  __shared__ __align__(16) short B_lds[128 * 64];
  const int b = blockIdx.y;
  const int n0 = blockIdx.x * 32;
  const int t = threadIdx.x;
  const int lane = t & 63, w = t >> 6;
  const int xq = n0 >> 10, yq = (n0 >> 5) & 31;   // uniform; z spans 0..31
  const float2* tabX = tabs;
  const float2* tabY = tabs + 2048;
  const float2* tabZ = tabs + 4096;

  f32x4 acc[2][2];
#pragma unroll
  for (int m = 0; m < 2; m++)
#pragma unroll
    for (int f = 0; f < 2; f++) acc[m][f] = (f32x4){0.f, 0.f, 0.f, 0.f};

  for (int ct = 0; ct < 5; ct++) {
    __syncthreads();
    {   // stage A: 32 rows x 64 k
      int r = t >> 3, g = t & 7;
      if (ct < 3) {
        int n = n0 + r;
        int x = n >> 10, y = (n >> 5) & 31, z = n & 31;
        int cell = (ct == 0) ? (z * 32 + x) : (ct == 1) ? (y * 32 + x) : (z * 32 + y);
        const int4 src = *reinterpret_cast<const int4*>(
            tri_tb + ((size_t)(b * 3 + ct) * 1024 + cell) * 64 + g * 8);
        *reinterpret_cast<int4*>(&A_lds[(r * 8 + (g ^ (r & 7))) * 8]) = src;
      } else {
        int i0 = (ct - 3) * 32 + g * 4;
        bf16x8v v;
#pragma unroll
        for (int q = 0; q < 4; q++) {
          int i = i0 + q;
          float2 exy = cmul(tabX[xq * 64 + i], tabY[yq * 64 + i]);
          float2 e = cmul(exy, tabZ[r * 64 + i]);   // z == r (32-aligned block)
          v[q * 2]     = f2b(e.y);   // sin
          v[q * 2 + 1] = f2b(e.x);   // cos
        }
        *reinterpret_cast<bf16x8v*>(&A_lds[(r * 8 + (g ^ (r & 7))) * 8]) = v;
      }
    }
    {   // stage B: 128 cols x 64 k
#pragma unroll
      for (int it = 0; it < 4; it++) {
        int u = it * 256 + t;
        int col = u >> 3, g = u & 7;
        const int4 src = *reinterpret_cast<const int4*>(
            Wqb_s + (size_t)col * 320 + ct * 64 + g * 8);
        *reinterpret_cast<int4*>(&B_lds[(col * 8 + (g ^ (col & 7))) * 8]) = src;
      }
    }
    __syncthreads();
#pragma unroll
    for (int ks = 0; ks < 2; ks++) {
      int kb = ks * 4 + (lane >> 4);
      bf16x8v a[2], bb[2];
#pragma unroll
      for (int m = 0; m < 2; m++) {
        int row = m * 16 + (lane & 15);
        a[m] = *reinterpret_cast<const bf16x8v*>(&A_lds[(row * 8 + (kb ^ (row & 7))) * 8]);
      }
#pragma unroll
      for (int f = 0; f < 2; f++) {
        int col = w * 32 + f * 16 + (lane & 15);
        bb[f] = *reinterpret_cast<const bf16x8v*>(&B_lds[(col * 8 + (kb ^ (col & 7))) * 8]);
      }
#pragma unroll
      for (int m = 0; m < 2; m++)
#pragma unroll
        for (int f = 0; f < 2; f++)
          acc[m][f] = __builtin_amdgcn_mfma_f32_16x16x32_bf16(a[m], bb[f], acc[m][f], 0, 0, 0);
    }
  }
  // epilogue: qh_g = acc + qcb (bf16)
#pragma unroll
  for (int m = 0; m < 2; m++)
#pragma unroll
    for (int f = 0; f < 2; f++)
#pragma unroll
      for (int reg = 0; reg < 4; reg++) {
        int row = m * 16 + (lane >> 4) * 4 + reg;
        int col = w * 32 + f * 16 + (lane & 15);
        qh_g[((size_t)b * NVOX + n0 + row) * 128 + col] = f2b(acc[m][f][reg] + qcb[col]);
      }
}

// ---------- attention (gather + softmax + PV), high occupancy ----------
__global__ __launch_bounds__(256) void k_attn(
    const short* __restrict__ qh_g, const short* __restrict__ k2b,
    const short* __restrict__ v2b, const float* __restrict__ proj,
    bf16* __restrict__ obuf) {
  __shared__ __align__(16) ushort sIr[160][4];
  __shared__ __align__(16) float sW4[160][4];
  __shared__ __align__(16) float lg[160 * 8];
  const int b = blockIdx.y;
  const int n0 = blockIdx.x * 32;
  const int t = threadIdx.x;

  // phase C: projection + bilinear taps (t < 160)
  if (t < 160) {
    int r = t / J5, j = t % J5;
    int n = n0 + r;
    int x = n >> 10, y = (n >> 5) & 31, z = n & 31;
    const float SC = (float)(1.0 + 0.1 + 1e-05);
    float fx = ((float)x / 31.0f - 0.5f) * 2.0f * SC;
    float fy = ((float)y / 31.0f - 0.5f) * 2.0f * SC;
    float fz = ((float)z / 31.0f - 0.5f) * 2.0f * SC;
    const float* P = proj + (size_t)(b * J5 + j) * 16;
    float pc0 = fmaf(fx, P[0], fmaf(fy, P[1], fmaf(fz, P[2],  P[3])));
    float pc1 = fmaf(fx, P[4], fmaf(fy, P[5], fmaf(fz, P[6],  P[7])));
    float pc2 = fmaf(fx, P[8], fmaf(fy, P[9], fmaf(fz, P[10], P[11])));
    float px = pc0 / pc2, py = pc1 / pc2;
    float gx = fminf(fmaxf((px / 223.0f - 0.5f) * 2.0f, -1.0f), 1.0f);
    float gy = fminf(fmaxf((py / 223.0f - 0.5f) * 2.0f, -1.0f), 1.0f);
    float ux = (gx + 1.0f) * 0.5f * 15.0f;
    float uy = (gy + 1.0f) * 0.5f * 15.0f;
    float fx0 = floorf(ux), fy0 = floorf(uy);
    int x0 = (int)fx0, y0 = (int)fy0;
    float wx = ux - fx0, wy = uy - fy0;
    int x1 = min(x0 + 1, 15), y1 = min(y0 + 1, 15);
    x0 = min(max(x0, 0), 15); y0 = min(max(y0, 0), 15);
    int rowb = (b * J5 + j) * 256;
    sIr[t][0] = (ushort)(rowb + y0 * 16 + x0);
    sIr[t][1] = (ushort)(rowb + y0 * 16 + x1);
    sIr[t][2] = (ushort)(rowb + y1 * 16 + x0);
    sIr[t][3] = (ushort)(rowb + y1 * 16 + x1);
    sW4[t][0] = (1.f - wx) * (1.f - wy);
    sW4[t][1] = wx * (1.f - wy);
    sW4[t][2] = (1.f - wx) * wy;
    sW4[t][3] = wx * wy;
  }
  __syncthreads();

  // phase D: logits — octet-per-thread, bf16x8 loads, single shfl
  {
    const int oct = t & 15, rjIdx = t >> 4;
    const int c0 = oct * 8;
#pragma unroll
    for (int it = 0; it < 10; it++) {
      int rj = rjIdx + it * 16;
      int r = rj / J5;
      ushort4 I4 = *reinterpret_cast<const ushort4*>(sIr[rj]);
      float4 W4 = *reinterpret_cast<const float4*>(sW4[rj]);
      bf16x8v t0 = *reinterpret_cast<const bf16x8v*>(k2b + (size_t)I4.x * 128 + c0);
      bf16x8v t1 = *reinterpret_cast<const bf16x8v*>(k2b + (size_t)I4.y * 128 + c0);
      bf16x8v t2 = *reinterpret_cast<const bf16x8v*>(k2b + (size_t)I4.z * 128 + c0);
      bf16x8v t3 = *reinterpret_cast<const bf16x8v*>(k2b + (size_t)I4.w * 128 + c0);
      bf16x8v q8 = *reinterpret_cast<const bf16x8v*>(qh_g + ((size_t)b * NVOX + n0 + r) * 128 + c0);
      float pv = 0.f;
#pragma unroll
      for (int e = 0; e < 8; e++) {
        float kh = fmaf(W4.x, b2f(t0[e]), fmaf(W4.y, b2f(t1[e]),
                   fmaf(W4.z, b2f(t2[e]), W4.w * b2f(t3[e]))));
        pv = fmaf(b2f(q8[e]), kh, pv);
      }
      pv += __shfl_xor(pv, 1);
      if (!(oct & 1)) lg[rj * 8 + (oct >> 1)] = pv * 0.25f;
    }
  }
  __syncthreads();

  // phase E: softmax over j per (r,h): 32*8 = 256 threads
  {
    int r = t >> 3, h = t & 7;
    float l[J5];
    float m = -1e30f;
#pragma unroll
    for (int j = 0; j < J5; j++) { l[j] = lg[(r * J5 + j) * 8 + h]; m = fmaxf(m, l[j]); }
    float sden = 0.f;
#pragma unroll
    for (int j = 0; j < J5; j++) { l[j] = expf(l[j] - m); sden += l[j]; }
    float inv = 1.0f / sden;
#pragma unroll
    for (int j = 0; j < J5; j++) lg[(r * J5 + j) * 8 + h] = l[j] * inv;
  }
  __syncthreads();

  // phase F: output — octet-per-thread accumulation, 2 rows/thread
  {
    const int oct = t & 15;
    const int c0 = oct * 8;
#pragma unroll
    for (int it = 0; it < 2; it++) {
      int r = (t >> 4) + it * 16;
      float o8[8] = {0.f, 0.f, 0.f, 0.f, 0.f, 0.f, 0.f, 0.f};
#pragma unroll
      for (int j = 0; j < J5; j++) {
        int rj = r * J5 + j;
        float aw = lg[rj * 8 + (oct >> 1)];
        ushort4 I4 = *reinterpret_cast<const ushort4*>(sIr[rj]);
        float4 W4 = *reinterpret_cast<const float4*>(sW4[rj]);
        float w0 = aw * W4.x, w1 = aw * W4.y, w2 = aw * W4.z, w3 = aw * W4.w;
        bf16x8v t0 = *reinterpret_cast<const bf16x8v*>(v2b + (size_t)I4.x * 128 + c0);
        bf16x8v t1 = *reinterpret_cast<const bf16x8v*>(v2b + (size_t)I4.y * 128 + c0);
        bf16x8v t2 = *reinterpret_cast<const bf16x8v*>(v2b + (size_t)I4.z * 128 + c0);
        bf16x8v t3 = *reinterpret_cast<const bf16x8v*>(v2b + (size_t)I4.w * 128 + c0);
#pragma unroll
        for (int e = 0; e < 8; e++) {
          o8[e] = fmaf(w0, b2f(t0[e]), o8[e]);
          o8[e] = fmaf(w1, b2f(t1[e]), o8[e]);
          o8[e] = fmaf(w2, b2f(t2[e]), o8[e]);
          o8[e] = fmaf(w3, b2f(t3[e]), o8[e]);
        }
      }
      bf16x8v out;
#pragma unroll
      for (int e = 0; e < 8; e++) out[e] = f2b(o8[e]);
      *reinterpret_cast<bf16x8v*>((short*)obuf + ((size_t)b * NVOX + n0 + r) * 128 + c0) = out;
    }
  }
}

// ---------- full-volume plane reductions (bf16x8 loads, 8 cells/block) ----------
__global__ __launch_bounds__(128) void k_reduce(const bf16* __restrict__ obuf,
                                                float* __restrict__ pacc) {
  int blk = blockIdx.x;
  int b = blockIdx.y;
  int t = threadIdx.x;
  int oct = t & 15, sub = t >> 4;
  int c0 = oct * 8;
  int cell = blk * 8 + sub;
  const short* ob = (const short*)obuf + (size_t)b * NVOX * 128;
  float a8[8] = {0.f, 0.f, 0.f, 0.f, 0.f, 0.f, 0.f, 0.f};
  size_t prow;
  if (cell < 1024) {
    int z = cell >> 5, x = cell & 31;
    for (int y = 0; y < 32; y++) {
      bf16x8v u = *reinterpret_cast<const bf16x8v*>(ob + ((size_t)(x * 1024 + y * 32 + z) * 128 + c0));
#pragma unroll
      for (int e = 0; e < 8; e++) a8[e] += b2f(u[e]);
    }
    prow = ((size_t)(b * 96 + z) * 32 + x) * 128 + c0;
  } else if (cell < 2048) {
    int e2 = cell - 1024;
    int y = e2 >> 5, x = e2 & 31;
    for (int z = 0; z < 32; z++) {
      bf16x8v u = *reinterpret_cast<const bf16x8v*>(ob + ((size_t)(x * 1024 + y * 32 + z) * 128 + c0));
#pragma unroll
      for (int e = 0; e < 8; e++) a8[e] += b2f(u[e]);
    }
    prow = ((size_t)(b * 96 + 32 + y) * 32 + x) * 128 + c0;
  } else {
    int e2 = cell - 2048;
    int z = e2 >> 5, y = e2 & 31;
    for (int x = 0; x < 32; x++) {
      bf16x8v u = *reinterpret_cast<const bf16x8v*>(ob + ((size_t)(x * 1024 + y * 32 + z) * 128 + c0));
#pragma unroll
      for (int e = 0; e < 8; e++) a8[e] += b2f(u[e]);
    }
    prow = ((size_t)(b * 96 + 64 + z) * 32 + y) * 128 + c0;
  }
  *(float4*)(&pacc[prow])     = (float4){a8[0], a8[1], a8[2], a8[3]};
  *(float4*)(&pacc[prow + 4]) = (float4){a8[4], a8[5], a8[6], a8[7]};
}

// ---------- final projection ----------
__global__ __launch_bounds__(128) void k_final(
    const float* __restrict__ pacc, const float* __restrict__ Wo,
    const float* __restrict__ obb, float* __restrict__ outp) {
  int bp = blockIdx.x;
  int b = bp / 96, prow = bp % 96;
  int obase = blockIdx.y * 16;
  __shared__ __align__(16) float lds[32 * 129];
  for (int idx = threadIdx.x; idx < 4096; idx += 128) {
    int col = idx >> 7, k = idx & 127;
    lds[col * 129 + k] = pacc[(size_t)bp * 32 * 128 + idx] * (1.0f / 32.0f);
  }
  __syncthreads();
  for (int e = threadIdx.x; e < 16 * 32; e += 128) {
    int o = obase + (e >> 5), col = e & 31;
    float val = obb[o];
    const float* wr = Wo + (size_t)o * 128;
    const float* lr = lds + col * 129;
    for (int k = 0; k < 128; k++) val = fmaf(wr[k], lr[k], val);
    outp[((size_t)(b * 64 + o) * 96 + prow) * 32 + col] = val;
  }
}

extern "C" void kernel_launch(void* const* d_in, const int* in_sizes, int n_in,
                              void* d_out, int out_size, void* d_ws, size_t ws_size,
                              hipStream_t stream) {
  const float* tp     = (const float*)d_in[0];
  const float* img    = (const float*)d_in[1];
  const float* proj   = (const float*)d_in[2];
  const float* k_w    = (const float*)d_in[4];
  const float* k_b    = (const float*)d_in[5];
  const float* q_w    = (const float*)d_in[6];
  const float* q_b    = (const float*)d_in[7];
  const float* v_w    = (const float*)d_in[8];
  const float* v_b    = (const float*)d_in[9];
  const float* in_w   = (const float*)d_in[10];
  const float* in_b   = (const float*)d_in[11];
  const float* out_w  = (const float*)d_in[12];
  const float* out_b  = (const float*)d_in[13];
  const float* proj_w = (const float*)d_in[14];
  const float* proj_b = (const float*)d_in[15];
  const int B = 2;

  float* ws = (float*)d_ws;
  size_t off = 0;
  short*  tri_tb = (short*)(ws + off);  off += 196608;   // 2*3*1024*64 bf16
  short*  Wkvb2  = (short*)(ws + off);  off += 188416;   // 256*1472 bf16
  short*  Wqb_s  = (short*)(ws + off);  off += 20480;    // 128*320 bf16
  short*  pe_tab = (short*)(ws + off);  off += 16384;    // 256*128 bf16
  float2* tabs   = (float2*)(ws + off); off += 12288;    // 3*32*64 cplx
  float*  qcb    = ws + off;            off += 128;
  float*  Wo     = ws + off;            off += 8192;
  float*  obb    = ws + off;            off += 64;
  short*  k2b    = (short*)(ws + off);  off += 163840;   // 2560*128 bf16
  short*  v2b    = (short*)(ws + off);  off += 163840;
  float*  pacc   = ws + off;            off += 786432;   // 2*96*32*128
  short*  qh_g   = (short*)(ws + off);  off += 4194304;  // 2*32768*128 bf16
  float*  zone   = ws + off;            off += 4194304;  // max(imgb, obuf)
  short*  imgb   = (short*)zone;
  bf16*   obuf   = (bf16*)zone;
  if (ws_size < off * sizeof(float)) return;  // ~40 MB needed; clean fail if short

  k_prep<<<dim3(NB_TOTAL), dim3(256), 0, stream>>>(
      img, tp, k_w, k_b, q_w, q_b, v_w, v_b, in_w, in_b, out_w, out_b, proj_w, proj_b,
      tabs, Wqb_s, Wo, qcb, obb, imgb, tri_tb, Wkvb2, pe_tab);
  k_gemm_kv<<<dim3(80, 4), dim3(256), 0, stream>>>(imgb, Wkvb2, pe_tab, k2b, v2b);
  k_qh<<<dim3(NVOX / 32, B), dim3(256), 0, stream>>>(tri_tb, Wqb_s, qcb, tabs, qh_g);
  k_attn<<<dim3(NVOX / 32, B), dim3(256), 0, stream>>>(qh_g, k2b, v2b, proj, obuf);
  k_reduce<<<dim3(384, B), dim3(128), 0, stream>>>(obuf, pacc);
  k_final<<<dim3(B * 96, 4), dim3(128), 0, stream>>>(pacc, Wo, obb, (float*)d_out);
}

// Round 8
// 110.470 us; speedup vs baseline: 1.0889x; 1.0841x over previous
//
#include <hip/hip_runtime.h>
#include <hip/hip_bf16.h>
#include <cstddef>

#define NVOX 32768
#define J5 5
#define KB2 1472           // folded K for kv GEMM: 1280 img | 128 pe | 64 const
typedef __hip_bfloat16 bf16;
typedef __attribute__((ext_vector_type(8))) short bf16x8v;
typedef __attribute__((ext_vector_type(4))) float f32x4;

static __device__ __forceinline__ float pe_val(int pos, int c) {
  float dv = expf((float)(c & ~1) * (-0.0719557841560639f));
  float arg = (float)pos * dv;
  return (c & 1) ? cosf(arg) : sinf(arg);
}
static __device__ __forceinline__ short f2b(float f) {
  __hip_bfloat16 h = __float2bfloat16(f);
  return *reinterpret_cast<short*>(&h);
}
static __device__ __forceinline__ float b2f(short s) {
  __hip_bfloat16 h = *reinterpret_cast<__hip_bfloat16*>(&s);
  return __bfloat162float(h);
}
static __device__ __forceinline__ float2 cmul(float2 a, float2 b) {
  return make_float2(a.x * b.x - a.y * b.y, a.x * b.y + a.y * b.x);
}

// block-range boundaries for k_prep sections (CVT section removed — gemm reads img directly)
#define NB_TABS   24
#define NB_WQPE   64
#define NB_WQC    96
#define NB_WO     32
#define NB_QCB    1
#define NB_TRI    1536
#define NB_FOLDW  1280
#define NB_PETAB  128
#define NB_WIN    128
#define NB_CB     1
#define B_TABS   0
#define B_WQPE   (B_TABS + NB_TABS)
#define B_WQC    (B_WQPE + NB_WQPE)
#define B_WO     (B_WQC + NB_WQC)
#define B_QCB    (B_WO + NB_WO)
#define B_TRI    (B_QCB + NB_QCB)
#define B_FOLDW  (B_TRI + NB_TRI)
#define B_PETAB  (B_FOLDW + NB_FOLDW)
#define B_WIN    (B_PETAB + NB_PETAB)
#define B_CB     (B_WIN + NB_WIN)
#define NB_TOTAL (B_CB + NB_CB)

// ---------- one merged prep kernel ----------
__global__ __launch_bounds__(256) void k_prep(
    const float* __restrict__ tp,
    const float* __restrict__ k_w, const float* __restrict__ k_b,
    const float* __restrict__ q_w, const float* __restrict__ q_b,
    const float* __restrict__ v_w, const float* __restrict__ v_b,
    const float* __restrict__ in_w, const float* __restrict__ in_b,
    const float* __restrict__ out_w, const float* __restrict__ out_b,
    const float* __restrict__ proj_w, const float* __restrict__ proj_b,
    float2* __restrict__ tabs, short* __restrict__ Wqb_s, float* __restrict__ Wo,
    float* __restrict__ qcb, float* __restrict__ obb,
    short* __restrict__ tri_tb, short* __restrict__ Wkvb2, short* __restrict__ pe_tab) {
  const int bx = blockIdx.x, t = threadIdx.x;

  if (bx < B_WQPE) {
    int idx = bx * 256 + t;
    if (idx < 6144) {
      int tb = idx >> 11, rem = idx & 2047;
      int pos = rem >> 6, i = rem & 63;
      float dv = expf((float)(2 * i) * (-0.0719557841560639f));
      float mult = (tb == 0) ? 1024.0f : (tb == 1) ? 32.0f : 1.0f;
      float ang = (float)pos * mult * dv;
      tabs[idx] = make_float2(cosf(ang), sinf(ang));
    }
  } else if (bx < B_WQC) {
    int e = (bx - B_WQPE) * 256 + t;
    int c = e >> 7, j = e & 127;
    Wqb_s[(size_t)c * 320 + 192 + j] = f2b(in_w[(size_t)c * 128 + j]);
  } else if (bx < B_WO) {
    int e = (bx - B_WQC) * 256 + t;
    int c = e / 192, k = e % 192;
    const float* ir = in_w + (size_t)c * 128;
    float acc = 0.f;
    for (int j = 0; j < 128; j++) acc = fmaf(ir[j], q_w[(size_t)j * 192 + k], acc);
    Wqb_s[(size_t)c * 320 + k] = f2b(acc);
  } else if (bx < B_QCB) {
    int e = (bx - B_WO) * 256 + t;
    int o = e >> 7, c = e & 127;
    const float* pr = proj_w + (size_t)o * 128;
    float acc = 0.f;
    for (int j = 0; j < 128; j++) acc = fmaf(pr[j], out_w[(size_t)j * 128 + c], acc);
    Wo[e] = acc;
  } else if (bx < B_TRI) {
    if (t < 128) {
      float acc = in_b[t];
      const float* ir = in_w + (size_t)t * 128;
      for (int j = 0; j < 128; j++) acc = fmaf(ir[j], q_b[j], acc);
      qcb[t] = acc;
    }
    if (t < 64) {
      float acc = proj_b[t];
      const float* pr = proj_w + (size_t)t * 128;
      for (int j = 0; j < 128; j++) acc = fmaf(pr[j], out_b[j], acc);
      obb[t] = acc;
    }
  } else if (bx < B_FOLDW) {
    int idx = (bx - B_TRI) * 256 + t;
    int cc   = idx & 63;
    int rem  = idx >> 6;
    int cell = rem & 1023;
    int segb = rem >> 10;
    int seg = segb % 3, b = segb / 3;
    int i = cell >> 5, j = cell & 31;
    tri_tb[idx] = f2b(tp[(((size_t)(b * 64 + cc)) * 96 + seg * 32 + i) * 32 + j]);
  } else if (bx < B_PETAB) {
    int u = (bx - B_FOLDW) * 256 + t;
    int c = u / 1280, k = u % 1280;
    const float* w = (c < 128) ? k_w : v_w;
    const float* ir = in_w + (size_t)(128 + c) * 128;
    float acc = 0.f;
    for (int j = 0; j < 128; j++) acc = fmaf(ir[j], w[(size_t)j * 1280 + k], acc);
    Wkvb2[(size_t)c * KB2 + k] = f2b(acc);
  } else if (bx < B_WIN) {
    int e = (bx - B_PETAB) * 256 + t;
    int p = e >> 7, c = e & 127;
    pe_tab[e] = f2b(pe_val(p, c));
  } else if (bx < B_CB) {
    int e = (bx - B_WIN) * 256 + t;
    int c = e >> 7, j = e & 127;
    Wkvb2[(size_t)c * KB2 + 1280 + j] = f2b(in_w[(size_t)(128 + c) * 128 + j]);
  } else {
    int c = t;
    int which = c >> 7;
    const float* bias = which ? v_b : k_b;
    const float* ir = in_w + (size_t)(128 + c) * 128;
    float acc = in_b[128 + c];
    for (int j = 0; j < 128; j++) acc = fmaf(bias[j], ir[j], acc);
    short* row = Wkvb2 + (size_t)c * KB2 + 1408;
    row[0] = f2b(acc);
    for (int k = 1; k < 64; k++) row[k] = 0;
  }
}

// ---------- MFMA GEMM: k2v2[2560][256] = [img|pe|1] @ Wkvb2^T ; img read f32 directly ----------
__global__ __launch_bounds__(256) void k_gemm_kv(
    const float* __restrict__ img, const short* __restrict__ Wkvb2,
    const short* __restrict__ pe_tab, short* __restrict__ k2b, short* __restrict__ v2b) {
  __shared__ __align__(16) short A_lds[32 * 64];
  __shared__ __align__(16) short B_lds[64 * 64];
  const int m0 = blockIdx.x * 32;
  const int nb0 = blockIdx.y * 64;
  const int t = threadIdx.x;
  const int lane = t & 63, w = t >> 6;
  const int wm = w & 1, wn = w >> 1;
  f32x4 acc[2];
  acc[0] = (f32x4){0.f, 0.f, 0.f, 0.f};
  acc[1] = (f32x4){0.f, 0.f, 0.f, 0.f};

  for (int ct = 0; ct < 23; ct++) {
    __syncthreads();
    {
      int r = t >> 3, g = t & 7;
      bf16x8v v;
      if (ct < 20) {
        int row = m0 + r;
        int bj = row >> 8, p = row & 255;
        const float* src = img + ((size_t)(bj * 257 + 1 + p)) * 1280 + ct * 64 + g * 8;
        float4 a0 = *(const float4*)src;
        float4 a1 = *(const float4*)(src + 4);
        v[0] = f2b(a0.x); v[1] = f2b(a0.y); v[2] = f2b(a0.z); v[3] = f2b(a0.w);
        v[4] = f2b(a1.x); v[5] = f2b(a1.y); v[6] = f2b(a1.z); v[7] = f2b(a1.w);
      } else if (ct < 22) {
        int p = (m0 + r) & 255;
        v = *reinterpret_cast<const bf16x8v*>(pe_tab + (size_t)p * 128 + (ct - 20) * 64 + g * 8);
      } else {
        v = (bf16x8v){0, 0, 0, 0, 0, 0, 0, 0};
        if (g == 0) v[0] = (short)0x3F80;
      }
      *reinterpret_cast<bf16x8v*>(&A_lds[(r * 8 + (g ^ (r & 7))) * 8]) = v;
    }
    {
#pragma unroll
      for (int it = 0; it < 2; it++) {
        int u = it * 256 + t;
        int r2 = u >> 3, g = u & 7;
        const int4 src = *reinterpret_cast<const int4*>(
            Wkvb2 + (size_t)(nb0 + r2) * KB2 + ct * 64 + g * 8);
        *reinterpret_cast<int4*>(&B_lds[(r2 * 8 + (g ^ (r2 & 7))) * 8]) = src;
      }
    }
    __syncthreads();
#pragma unroll
    for (int ks = 0; ks < 2; ks++) {
      int kb = ks * 4 + (lane >> 4);
      int arow = wm * 16 + (lane & 15);
      bf16x8v a = *reinterpret_cast<const bf16x8v*>(&A_lds[(arow * 8 + (kb ^ (arow & 7))) * 8]);
#pragma unroll
      for (int f = 0; f < 2; f++) {
        int bcol = wn * 32 + f * 16 + (lane & 15);
        bf16x8v bb = *reinterpret_cast<const bf16x8v*>(&B_lds[(bcol * 8 + (kb ^ (bcol & 7))) * 8]);
        acc[f] = __builtin_amdgcn_mfma_f32_16x16x32_bf16(a, bb, acc[f], 0, 0, 0);
      }
    }
  }
#pragma unroll
  for (int f = 0; f < 2; f++) {
#pragma unroll
    for (int reg = 0; reg < 4; reg++) {
      int grow = m0 + wm * 16 + (lane >> 4) * 4 + reg;
      int gcol = nb0 + wn * 32 + f * 16 + (lane & 15);
      int which = gcol >> 7, c = gcol & 127;
      short* dst = which ? v2b : k2b;
      dst[(size_t)grow * 128 + c] = f2b(acc[f][reg]);
    }
  }
}

// ---------- qh GEMM (M=64 tile): qh = [tri|pe] @ Wqb^T + qcb, bf16 out ----------
__global__ __launch_bounds__(256) void k_qh(
    const short* __restrict__ tri_tb, const short* __restrict__ Wqb_s,
    const float* __restrict__ qcb, const float2* __restrict__ tabs,
    short* __restrict__ qh_g) {
  __shared__ __align__(16) short A_lds[64 * 64];    // 8 KB
  __shared__ __align__(16) short B_lds[128 * 64];   // 16 KB
  const int b = blockIdx.y;
  const int n0 = blockIdx.x * 64;                   // 64 | n0 : x fixed, y in {yq0, yq0+1}, z 0..31
  const int t = threadIdx.x;
  const int lane = t & 63, w = t >> 6;
  const int xq = n0 >> 10, yq0 = (n0 >> 5) & 31;
  const float2* tabX = tabs;
  const float2* tabY = tabs + 2048;
  const float2* tabZ = tabs + 4096;

  f32x4 acc[4][2];
#pragma unroll
  for (int m = 0; m < 4; m++)
#pragma unroll
    for (int f = 0; f < 2; f++) acc[m][f] = (f32x4){0.f, 0.f, 0.f, 0.f};

  for (int ct = 0; ct < 5; ct++) {
    __syncthreads();
    {   // stage A: 64 rows x 64 k (2 int4/thread)
#pragma unroll
      for (int it = 0; it < 2; it++) {
        int u = it * 256 + t;
        int r = u >> 3, g = u & 7;
        if (ct < 3) {
          int n = n0 + r;
          int x = n >> 10, y = (n >> 5) & 31, z = n & 31;
          int cell = (ct == 0) ? (z * 32 + x) : (ct == 1) ? (y * 32 + x) : (z * 32 + y);
          const int4 src = *reinterpret_cast<const int4*>(
              tri_tb + ((size_t)(b * 3 + ct) * 1024 + cell) * 64 + g * 8);
          *reinterpret_cast<int4*>(&A_lds[(r * 8 + (g ^ (r & 7))) * 8]) = src;
        } else {
          int i0 = (ct - 3) * 32 + g * 4;
          int z = r & 31, y = yq0 + (r >> 5);
          bf16x8v v;
#pragma unroll
          for (int q = 0; q < 4; q++) {
            int i = i0 + q;
            float2 exy = cmul(tabX[xq * 64 + i], tabY[y * 64 + i]);
            float2 e = cmul(exy, tabZ[z * 64 + i]);
            v[q * 2]     = f2b(e.y);   // sin
            v[q * 2 + 1] = f2b(e.x);   // cos
          }
          *reinterpret_cast<bf16x8v*>(&A_lds[(r * 8 + (g ^ (r & 7))) * 8]) = v;
        }
      }
    }
    {   // stage B: 128 cols x 64 k (4 int4/thread)
#pragma unroll
      for (int it = 0; it < 4; it++) {
        int u = it * 256 + t;
        int col = u >> 3, g = u & 7;
        const int4 src = *reinterpret_cast<const int4*>(
            Wqb_s + (size_t)col * 320 + ct * 64 + g * 8);
        *reinterpret_cast<int4*>(&B_lds[(col * 8 + (g ^ (col & 7))) * 8]) = src;
      }
    }
    __syncthreads();
#pragma unroll
    for (int ks = 0; ks < 2; ks++) {
      int kb = ks * 4 + (lane >> 4);
      bf16x8v a[4], bb[2];
#pragma unroll
      for (int m = 0; m < 4; m++) {
        int row = m * 16 + (lane & 15);
        a[m] = *reinterpret_cast<const bf16x8v*>(&A_lds[(row * 8 + (kb ^ (row & 7))) * 8]);
      }
#pragma unroll
      for (int f = 0; f < 2; f++) {
        int col = w * 32 + f * 16 + (lane & 15);
        bb[f] = *reinterpret_cast<const bf16x8v*>(&B_lds[(col * 8 + (kb ^ (col & 7))) * 8]);
      }
#pragma unroll
      for (int m = 0; m < 4; m++)
#pragma unroll
        for (int f = 0; f < 2; f++)
          acc[m][f] = __builtin_amdgcn_mfma_f32_16x16x32_bf16(a[m], bb[f], acc[m][f], 0, 0, 0);
    }
  }
  // epilogue: qh_g = acc + qcb (bf16)
#pragma unroll
  for (int m = 0; m < 4; m++)
#pragma unroll
    for (int f = 0; f < 2; f++)
#pragma unroll
      for (int reg = 0; reg < 4; reg++) {
        int row = m * 16 + (lane >> 4) * 4 + reg;
        int col = w * 32 + f * 16 + (lane & 15);
        qh_g[((size_t)b * NVOX + n0 + row) * 128 + col] = f2b(acc[m][f][reg] + qcb[col]);
      }
}

// ---------- attention (gather + softmax + PV), high occupancy ----------
__global__ __launch_bounds__(256) void k_attn(
    const short* __restrict__ qh_g, const short* __restrict__ k2b,
    const short* __restrict__ v2b, const float* __restrict__ proj,
    bf16* __restrict__ obuf) {
  __shared__ __align__(16) ushort sIr[160][4];
  __shared__ __align__(16) float sW4[160][4];
  __shared__ __align__(16) float lg[160 * 8];
  const int b = blockIdx.y;
  const int n0 = blockIdx.x * 32;
  const int t = threadIdx.x;

  // phase C: projection + bilinear taps (t < 160)
  if (t < 160) {
    int r = t / J5, j = t % J5;
    int n = n0 + r;
    int x = n >> 10, y = (n >> 5) & 31, z = n & 31;
    const float SC = (float)(1.0 + 0.1 + 1e-05);
    float fx = ((float)x / 31.0f - 0.5f) * 2.0f * SC;
    float fy = ((float)y / 31.0f - 0.5f) * 2.0f * SC;
    float fz = ((float)z / 31.0f - 0.5f) * 2.0f * SC;
    const float* P = proj + (size_t)(b * J5 + j) * 16;
    float pc0 = fmaf(fx, P[0], fmaf(fy, P[1], fmaf(fz, P[2],  P[3])));
    float pc1 = fmaf(fx, P[4], fmaf(fy, P[5], fmaf(fz, P[6],  P[7])));
    float pc2 = fmaf(fx, P[8], fmaf(fy, P[9], fmaf(fz, P[10], P[11])));
    float px = pc0 / pc2, py = pc1 / pc2;
    float gx = fminf(fmaxf((px / 223.0f - 0.5f) * 2.0f, -1.0f), 1.0f);
    float gy = fminf(fmaxf((py / 223.0f - 0.5f) * 2.0f, -1.0f), 1.0f);
    float ux = (gx + 1.0f) * 0.5f * 15.0f;
    float uy = (gy + 1.0f) * 0.5f * 15.0f;
    float fx0 = floorf(ux), fy0 = floorf(uy);
    int x0 = (int)fx0, y0 = (int)fy0;
    float wx = ux - fx0, wy = uy - fy0;
    int x1 = min(x0 + 1, 15), y1 = min(y0 + 1, 15);
    x0 = min(max(x0, 0), 15); y0 = min(max(y0, 0), 15);
    int rowb = (b * J5 + j) * 256;
    sIr[t][0] = (ushort)(rowb + y0 * 16 + x0);
    sIr[t][1] = (ushort)(rowb + y0 * 16 + x1);
    sIr[t][2] = (ushort)(rowb + y1 * 16 + x0);
    sIr[t][3] = (ushort)(rowb + y1 * 16 + x1);
    sW4[t][0] = (1.f - wx) * (1.f - wy);
    sW4[t][1] = wx * (1.f - wy);
    sW4[t][2] = (1.f - wx) * wy;
    sW4[t][3] = wx * wy;
  }
  __syncthreads();

  // phase D: logits — octet-per-thread, bf16x8 loads, single shfl
  {
    const int oct = t & 15, rjIdx = t >> 4;
    const int c0 = oct * 8;
#pragma unroll
    for (int it = 0; it < 10; it++) {
      int rj = rjIdx + it * 16;
      int r = rj / J5;
      ushort4 I4 = *reinterpret_cast<const ushort4*>(sIr[rj]);
      float4 W4 = *reinterpret_cast<const float4*>(sW4[rj]);
      bf16x8v t0 = *reinterpret_cast<const bf16x8v*>(k2b + (size_t)I4.x * 128 + c0);
      bf16x8v t1 = *reinterpret_cast<const bf16x8v*>(k2b + (size_t)I4.y * 128 + c0);
      bf16x8v t2 = *reinterpret_cast<const bf16x8v*>(k2b + (size_t)I4.z * 128 + c0);
      bf16x8v t3 = *reinterpret_cast<const bf16x8v*>(k2b + (size_t)I4.w * 128 + c0);
      bf16x8v q8 = *reinterpret_cast<const bf16x8v*>(qh_g + ((size_t)b * NVOX + n0 + r) * 128 + c0);
      float pv = 0.f;
#pragma unroll
      for (int e = 0; e < 8; e++) {
        float kh = fmaf(W4.x, b2f(t0[e]), fmaf(W4.y, b2f(t1[e]),
                   fmaf(W4.z, b2f(t2[e]), W4.w * b2f(t3[e]))));
        pv = fmaf(b2f(q8[e]), kh, pv);
      }
      pv += __shfl_xor(pv, 1);
      if (!(oct & 1)) lg[rj * 8 + (oct >> 1)] = pv * 0.25f;
    }
  }
  __syncthreads();

  // phase E: softmax over j per (r,h): 32*8 = 256 threads
  {
    int r = t >> 3, h = t & 7;
    float l[J5];
    float m = -1e30f;
#pragma unroll
    for (int j = 0; j < J5; j++) { l[j] = lg[(r * J5 + j) * 8 + h]; m = fmaxf(m, l[j]); }
    float sden = 0.f;
#pragma unroll
    for (int j = 0; j < J5; j++) { l[j] = expf(l[j] - m); sden += l[j]; }
    float inv = 1.0f / sden;
#pragma unroll
    for (int j = 0; j < J5; j++) lg[(r * J5 + j) * 8 + h] = l[j] * inv;
  }
  __syncthreads();

  // phase F: output — octet-per-thread accumulation, 2 rows/thread
  {
    const int oct = t & 15;
    const int c0 = oct * 8;
#pragma unroll
    for (int it = 0; it < 2; it++) {
      int r = (t >> 4) + it * 16;
      float o8[8] = {0.f, 0.f, 0.f, 0.f, 0.f, 0.f, 0.f, 0.f};
#pragma unroll
      for (int j = 0; j < J5; j++) {
        int rj = r * J5 + j;
        float aw = lg[rj * 8 + (oct >> 1)];
        ushort4 I4 = *reinterpret_cast<const ushort4*>(sIr[rj]);
        float4 W4 = *reinterpret_cast<const float4*>(sW4[rj]);
        float w0 = aw * W4.x, w1 = aw * W4.y, w2 = aw * W4.z, w3 = aw * W4.w;
        bf16x8v t0 = *reinterpret_cast<const bf16x8v*>(v2b + (size_t)I4.x * 128 + c0);
        bf16x8v t1 = *reinterpret_cast<const bf16x8v*>(v2b + (size_t)I4.y * 128 + c0);
        bf16x8v t2 = *reinterpret_cast<const bf16x8v*>(v2b + (size_t)I4.z * 128 + c0);
        bf16x8v t3 = *reinterpret_cast<const bf16x8v*>(v2b + (size_t)I4.w * 128 + c0);
#pragma unroll
        for (int e = 0; e < 8; e++) {
          o8[e] = fmaf(w0, b2f(t0[e]), o8[e]);
          o8[e] = fmaf(w1, b2f(t1[e]), o8[e]);
          o8[e] = fmaf(w2, b2f(t2[e]), o8[e]);
          o8[e] = fmaf(w3, b2f(t3[e]), o8[e]);
        }
      }
      bf16x8v out;
#pragma unroll
      for (int e = 0; e < 8; e++) out[e] = f2b(o8[e]);
      *reinterpret_cast<bf16x8v*>((short*)obuf + ((size_t)b * NVOX + n0 + r) * 128 + c0) = out;
    }
  }
}

// ---------- full-volume plane reductions (bf16x8 loads, 8 cells/block) ----------
__global__ __launch_bounds__(128) void k_reduce(const bf16* __restrict__ obuf,
                                                float* __restrict__ pacc) {
  int blk = blockIdx.x;
  int b = blockIdx.y;
  int t = threadIdx.x;
  int oct = t & 15, sub = t >> 4;
  int c0 = oct * 8;
  int cell = blk * 8 + sub;
  const short* ob = (const short*)obuf + (size_t)b * NVOX * 128;
  float a8[8] = {0.f, 0.f, 0.f, 0.f, 0.f, 0.f, 0.f, 0.f};
  size_t prow;
  if (cell < 1024) {
    int z = cell >> 5, x = cell & 31;
    for (int y = 0; y < 32; y++) {
      bf16x8v u = *reinterpret_cast<const bf16x8v*>(ob + ((size_t)(x * 1024 + y * 32 + z) * 128 + c0));
#pragma unroll
      for (int e = 0; e < 8; e++) a8[e] += b2f(u[e]);
    }
    prow = ((size_t)(b * 96 + z) * 32 + x) * 128 + c0;
  } else if (cell < 2048) {
    int e2 = cell - 1024;
    int y = e2 >> 5, x = e2 & 31;
    for (int z = 0; z < 32; z++) {
      bf16x8v u = *reinterpret_cast<const bf16x8v*>(ob + ((size_t)(x * 1024 + y * 32 + z) * 128 + c0));
#pragma unroll
      for (int e = 0; e < 8; e++) a8[e] += b2f(u[e]);
    }
    prow = ((size_t)(b * 96 + 32 + y) * 32 + x) * 128 + c0;
  } else {
    int e2 = cell - 2048;
    int z = e2 >> 5, y = e2 & 31;
    for (int x = 0; x < 32; x++) {
      bf16x8v u = *reinterpret_cast<const bf16x8v*>(ob + ((size_t)(x * 1024 + y * 32 + z) * 128 + c0));
#pragma unroll
      for (int e = 0; e < 8; e++) a8[e] += b2f(u[e]);
    }
    prow = ((size_t)(b * 96 + 64 + z) * 32 + y) * 128 + c0;
  }
  *(float4*)(&pacc[prow])     = (float4){a8[0], a8[1], a8[2], a8[3]};
  *(float4*)(&pacc[prow + 4]) = (float4){a8[4], a8[5], a8[6], a8[7]};
}

// ---------- final projection ----------
__global__ __launch_bounds__(128) void k_final(
    const float* __restrict__ pacc, const float* __restrict__ Wo,
    const float* __restrict__ obb, float* __restrict__ outp) {
  int bp = blockIdx.x;
  int b = bp / 96, prow = bp % 96;
  int obase = blockIdx.y * 16;
  __shared__ __align__(16) float lds[32 * 129];
  for (int idx = threadIdx.x; idx < 4096; idx += 128) {
    int col = idx >> 7, k = idx & 127;
    lds[col * 129 + k] = pacc[(size_t)bp * 32 * 128 + idx] * (1.0f / 32.0f);
  }
  __syncthreads();
  for (int e = threadIdx.x; e < 16 * 32; e += 128) {
    int o = obase + (e >> 5), col = e & 31;
    float val = obb[o];
    const float* wr = Wo + (size_t)o * 128;
    const float* lr = lds + col * 129;
    for (int k = 0; k < 128; k++) val = fmaf(wr[k], lr[k], val);
    outp[((size_t)(b * 64 + o) * 96 + prow) * 32 + col] = val;
  }
}

extern "C" void kernel_launch(void* const* d_in, const int* in_sizes, int n_in,
                              void* d_out, int out_size, void* d_ws, size_t ws_size,
                              hipStream_t stream) {
  const float* tp     = (const float*)d_in[0];
  const float* img    = (const float*)d_in[1];
  const float* proj   = (const float*)d_in[2];
  const float* k_w    = (const float*)d_in[4];
  const float* k_b    = (const float*)d_in[5];
  const float* q_w    = (const float*)d_in[6];
  const float* q_b    = (const float*)d_in[7];
  const float* v_w    = (const float*)d_in[8];
  const float* v_b    = (const float*)d_in[9];
  const float* in_w   = (const float*)d_in[10];
  const float* in_b   = (const float*)d_in[11];
  const float* out_w  = (const float*)d_in[12];
  const float* out_b  = (const float*)d_in[13];
  const float* proj_w = (const float*)d_in[14];
  const float* proj_b = (const float*)d_in[15];
  const int B = 2;

  float* ws = (float*)d_ws;
  size_t off = 0;
  short*  tri_tb = (short*)(ws + off);  off += 196608;   // 2*3*1024*64 bf16
  short*  Wkvb2  = (short*)(ws + off);  off += 188416;   // 256*1472 bf16
  short*  Wqb_s  = (short*)(ws + off);  off += 20480;    // 128*320 bf16
  short*  pe_tab = (short*)(ws + off);  off += 16384;    // 256*128 bf16
  float2* tabs   = (float2*)(ws + off); off += 12288;    // 3*32*64 cplx
  float*  qcb    = ws + off;            off += 128;
  float*  Wo     = ws + off;            off += 8192;
  float*  obb    = ws + off;            off += 64;
  short*  k2b    = (short*)(ws + off);  off += 163840;   // 2560*128 bf16
  short*  v2b    = (short*)(ws + off);  off += 163840;
  float*  pacc   = ws + off;            off += 786432;   // 2*96*32*128
  short*  qh_g   = (short*)(ws + off);  off += 4194304;  // 2*32768*128 bf16
  bf16*   obuf   = (bf16*)(ws + off);   off += 2097152;  // 2*32768*128 bf16
  if (ws_size < off * sizeof(float)) return;  // ~31.4 MB needed; clean fail if short

  k_prep<<<dim3(NB_TOTAL), dim3(256), 0, stream>>>(
      tp, k_w, k_b, q_w, q_b, v_w, v_b, in_w, in_b, out_w, out_b, proj_w, proj_b,
      tabs, Wqb_s, Wo, qcb, obb, tri_tb, Wkvb2, pe_tab);
  k_gemm_kv<<<dim3(80, 4), dim3(256), 0, stream>>>(img, Wkvb2, pe_tab, k2b, v2b);
  k_qh<<<dim3(NVOX / 64, B), dim3(256), 0, stream>>>(tri_tb, Wqb_s, qcb, tabs, qh_g);
  k_attn<<<dim3(NVOX / 32, B), dim3(256), 0, stream>>>(qh_g, k2b, v2b, proj, obuf);
  k_reduce<<<dim3(384, B), dim3(128), 0, stream>>>(obuf, pacc);
  k_final<<<dim3(B * 96, 4), dim3(128), 0, stream>>>(pacc, Wo, obb, (float*)d_out);
}

// Round 9
// 95.538 us; speedup vs baseline: 1.2590x; 1.1563x over previous
//
#include <hip/hip_runtime.h>
#include <hip/hip_bf16.h>
#include <cstddef>

#define NVOX 32768
#define J5 5
#define KB2 1472           // folded K for kv GEMM: 1280 img | 128 pe | 64 const
typedef __hip_bfloat16 bf16;
typedef __attribute__((ext_vector_type(8))) short bf16x8v;
typedef __attribute__((ext_vector_type(4))) float f32x4;

static __device__ __forceinline__ float pe_val(int pos, int c) {
  float dv = expf((float)(c & ~1) * (-0.0719557841560639f));
  float arg = (float)pos * dv;
  return (c & 1) ? cosf(arg) : sinf(arg);
}
static __device__ __forceinline__ short f2b(float f) {
  __hip_bfloat16 h = __float2bfloat16(f);
  return *reinterpret_cast<short*>(&h);
}
static __device__ __forceinline__ float b2f(short s) {
  __hip_bfloat16 h = *reinterpret_cast<__hip_bfloat16*>(&s);
  return __bfloat162float(h);
}
static __device__ __forceinline__ float2 cmul(float2 a, float2 b) {
  return make_float2(a.x * b.x - a.y * b.y, a.x * b.y + a.y * b.x);
}

// block-range boundaries for k_prep sections
#define NB_TABS   24      // tabs: 6144
#define NB_WQPE   64      // Wqb pe-part
#define NB_WQC    96      // Wqc fold
#define NB_WO     32      // Wo fold
#define NB_QCB    1       // qcb+obb
#define NB_TRI2   96      // LDS-tiled tri transpose: 6 (b,seg) x 16 tiles
#define NB_FOLDW  1280    // Wkvb2[:,0:1280]
#define NB_PETAB  128     // pe_tab
#define NB_WIN    128     // Wkvb2[:,1280:1408]
#define NB_CB     1       // Wkvb2[:,1408:1472]
#define B_TABS   0
#define B_WQPE   (B_TABS + NB_TABS)
#define B_WQC    (B_WQPE + NB_WQPE)
#define B_WO     (B_WQC + NB_WQC)
#define B_QCB    (B_WO + NB_WO)
#define B_TRI2   (B_QCB + NB_QCB)
#define B_FOLDW  (B_TRI2 + NB_TRI2)
#define B_PETAB  (B_FOLDW + NB_FOLDW)
#define B_WIN    (B_PETAB + NB_PETAB)
#define B_CB     (B_WIN + NB_WIN)
#define NB_TOTAL (B_CB + NB_CB)   // 1850

// ---------- one merged prep kernel ----------
__global__ __launch_bounds__(256) void k_prep(
    const float* __restrict__ tp,
    const float* __restrict__ k_w, const float* __restrict__ k_b,
    const float* __restrict__ q_w, const float* __restrict__ q_b,
    const float* __restrict__ v_w, const float* __restrict__ v_b,
    const float* __restrict__ in_w, const float* __restrict__ in_b,
    const float* __restrict__ out_w, const float* __restrict__ out_b,
    const float* __restrict__ proj_w, const float* __restrict__ proj_b,
    float2* __restrict__ tabs, short* __restrict__ Wqb_s, float* __restrict__ Wo,
    float* __restrict__ qcb, float* __restrict__ obb,
    short* __restrict__ tri_tb, short* __restrict__ Wkvb2, short* __restrict__ pe_tab) {
  __shared__ short tile_s[64][65];
  const int bx = blockIdx.x, t = threadIdx.x;

  if (bx < B_WQPE) {
    int idx = bx * 256 + t;
    if (idx < 6144) {
      int tb = idx >> 11, rem = idx & 2047;
      int pos = rem >> 6, i = rem & 63;
      float dv = expf((float)(2 * i) * (-0.0719557841560639f));
      float mult = (tb == 0) ? 1024.0f : (tb == 1) ? 32.0f : 1.0f;
      float ang = (float)pos * mult * dv;
      tabs[idx] = make_float2(cosf(ang), sinf(ang));
    }
  } else if (bx < B_WQC) {
    int e = (bx - B_WQPE) * 256 + t;
    int c = e >> 7, j = e & 127;
    Wqb_s[(size_t)c * 320 + 192 + j] = f2b(in_w[(size_t)c * 128 + j]);
  } else if (bx < B_WO) {
    int e = (bx - B_WQC) * 256 + t;
    int c = e / 192, k = e % 192;
    const float* ir = in_w + (size_t)c * 128;
    float acc = 0.f;
    for (int j = 0; j < 128; j++) acc = fmaf(ir[j], q_w[(size_t)j * 192 + k], acc);
    Wqb_s[(size_t)c * 320 + k] = f2b(acc);
  } else if (bx < B_QCB) {
    int e = (bx - B_WO) * 256 + t;
    int o = e >> 7, c = e & 127;
    const float* pr = proj_w + (size_t)o * 128;
    float acc = 0.f;
    for (int j = 0; j < 128; j++) acc = fmaf(pr[j], out_w[(size_t)j * 128 + c], acc);
    Wo[e] = acc;
  } else if (bx < B_TRI2) {
    if (t < 128) {
      float acc = in_b[t];
      const float* ir = in_w + (size_t)t * 128;
      for (int j = 0; j < 128; j++) acc = fmaf(ir[j], q_b[j], acc);
      qcb[t] = acc;
    }
    if (t < 64) {
      float acc = proj_b[t];
      const float* pr = proj_w + (size_t)t * 128;
      for (int j = 0; j < 128; j++) acc = fmaf(pr[j], out_b[j], acc);
      obb[t] = acc;
    }
  } else if (bx < B_FOLDW) {
    // LDS-tiled tri transpose: tt[((b*3+seg)*1024 + cell)*64 + cc] = tp[((b*64+cc)*96 + seg*32 + i)*32 + j]
    int b3 = bx - B_TRI2;              // 0..95
    int segb = b3 >> 4, tile = b3 & 15;
    int b = segb / 3, seg = segb % 3;
    int cc = t >> 2, q = t & 3;
    // read: 2 i-rows x 8 floats each (coalesced float4 pairs)
#pragma unroll
    for (int di = 0; di < 2; di++) {
      int i = tile * 2 + di;
      const float* src = tp + (((size_t)(b * 64 + cc)) * 96 + seg * 32 + i) * 32 + q * 8;
      float4 a0 = *(const float4*)src;
      float4 a1 = *(const float4*)(src + 4);
      short* dst = &tile_s[cc][di * 32 + q * 8];
      dst[0] = f2b(a0.x); dst[1] = f2b(a0.y); dst[2] = f2b(a0.z); dst[3] = f2b(a0.w);
      dst[4] = f2b(a1.x); dst[5] = f2b(a1.y); dst[6] = f2b(a1.z); dst[7] = f2b(a1.w);
    }
    __syncthreads();
    // write: cell' = t>>2, cc block of 16 (contiguous bf16x8 x2)
    int cp = t >> 2;
    int cc0 = q * 16;
    bf16x8v v0, v1;
#pragma unroll
    for (int e = 0; e < 8; e++) { v0[e] = tile_s[cc0 + e][cp]; v1[e] = tile_s[cc0 + 8 + e][cp]; }
    short* outp = tri_tb + (((size_t)(b * 3 + seg) * 1024) + tile * 64 + cp) * 64 + cc0;
    *reinterpret_cast<bf16x8v*>(outp) = v0;
    *reinterpret_cast<bf16x8v*>(outp + 8) = v1;
  } else if (bx < B_PETAB) {
    int u = (bx - B_FOLDW) * 256 + t;
    int c = u / 1280, k = u % 1280;
    const float* w = (c < 128) ? k_w : v_w;
    const float* ir = in_w + (size_t)(128 + c) * 128;
    float acc = 0.f;
    for (int j = 0; j < 128; j++) acc = fmaf(ir[j], w[(size_t)j * 1280 + k], acc);
    Wkvb2[(size_t)c * KB2 + k] = f2b(acc);
  } else if (bx < B_WIN) {
    int e = (bx - B_PETAB) * 256 + t;
    int p = e >> 7, c = e & 127;
    pe_tab[e] = f2b(pe_val(p, c));
  } else if (bx < B_CB) {
    int e = (bx - B_WIN) * 256 + t;
    int c = e >> 7, j = e & 127;
    Wkvb2[(size_t)c * KB2 + 1280 + j] = f2b(in_w[(size_t)(128 + c) * 128 + j]);
  } else {
    int c = t;
    int which = c >> 7;
    const float* bias = which ? v_b : k_b;
    const float* ir = in_w + (size_t)(128 + c) * 128;
    float acc = in_b[128 + c];
    for (int j = 0; j < 128; j++) acc = fmaf(bias[j], ir[j], acc);
    short* row = Wkvb2 + (size_t)c * KB2 + 1408;
    row[0] = f2b(acc);
    for (int k = 1; k < 64; k++) row[k] = 0;
  }
}

// ---------- merged GEMMs: blocks [0,320) = kv GEMM ; [320, 1344) = qh GEMM ----------
#define NKV 320
__global__ __launch_bounds__(256) void k_qkv(
    const float* __restrict__ img, const short* __restrict__ Wkvb2,
    const short* __restrict__ pe_tab, short* __restrict__ k2b, short* __restrict__ v2b,
    const short* __restrict__ tri_tb, const short* __restrict__ Wqb_s,
    const float* __restrict__ qcb, const float2* __restrict__ tabs,
    short* __restrict__ qh_g) {
  __shared__ __align__(16) short A_lds[64 * 64];
  __shared__ __align__(16) short B_lds[128 * 64];
  const int t = threadIdx.x;
  const int lane = t & 63, w = t >> 6;

  if (blockIdx.x < NKV) {
    // ---- kv GEMM: tile 32x64, K=1472 ----
    const int kvid = blockIdx.x;
    const int m0 = (kvid >> 2) * 32;
    const int nb0 = (kvid & 3) * 64;
    const int wm = w & 1, wn = w >> 1;
    f32x4 acc[2];
    acc[0] = (f32x4){0.f, 0.f, 0.f, 0.f};
    acc[1] = (f32x4){0.f, 0.f, 0.f, 0.f};
    for (int ct = 0; ct < 23; ct++) {
      __syncthreads();
      {
        int r = t >> 3, g = t & 7;
        bf16x8v v;
        if (ct < 20) {
          int row = m0 + r;
          int bj = row >> 8, p = row & 255;
          const float* src = img + ((size_t)(bj * 257 + 1 + p)) * 1280 + ct * 64 + g * 8;
          float4 a0 = *(const float4*)src;
          float4 a1 = *(const float4*)(src + 4);
          v[0] = f2b(a0.x); v[1] = f2b(a0.y); v[2] = f2b(a0.z); v[3] = f2b(a0.w);
          v[4] = f2b(a1.x); v[5] = f2b(a1.y); v[6] = f2b(a1.z); v[7] = f2b(a1.w);
        } else if (ct < 22) {
          int p = (m0 + r) & 255;
          v = *reinterpret_cast<const bf16x8v*>(pe_tab + (size_t)p * 128 + (ct - 20) * 64 + g * 8);
        } else {
          v = (bf16x8v){0, 0, 0, 0, 0, 0, 0, 0};
          if (g == 0) v[0] = (short)0x3F80;
        }
        *reinterpret_cast<bf16x8v*>(&A_lds[(r * 8 + (g ^ (r & 7))) * 8]) = v;
      }
      {
#pragma unroll
        for (int it = 0; it < 2; it++) {
          int u = it * 256 + t;
          int r2 = u >> 3, g = u & 7;
          const int4 src = *reinterpret_cast<const int4*>(
              Wkvb2 + (size_t)((kvid & 3) * 64 + r2) * KB2 + ct * 64 + g * 8);
          *reinterpret_cast<int4*>(&B_lds[(r2 * 8 + (g ^ (r2 & 7))) * 8]) = src;
        }
      }
      __syncthreads();
#pragma unroll
      for (int ks = 0; ks < 2; ks++) {
        int kb = ks * 4 + (lane >> 4);
        int arow = wm * 16 + (lane & 15);
        bf16x8v a = *reinterpret_cast<const bf16x8v*>(&A_lds[(arow * 8 + (kb ^ (arow & 7))) * 8]);
#pragma unroll
        for (int f = 0; f < 2; f++) {
          int bcol = wn * 32 + f * 16 + (lane & 15);
          bf16x8v bb = *reinterpret_cast<const bf16x8v*>(&B_lds[(bcol * 8 + (kb ^ (bcol & 7))) * 8]);
          acc[f] = __builtin_amdgcn_mfma_f32_16x16x32_bf16(a, bb, acc[f], 0, 0, 0);
        }
      }
    }
#pragma unroll
    for (int f = 0; f < 2; f++) {
#pragma unroll
      for (int reg = 0; reg < 4; reg++) {
        int grow = m0 + wm * 16 + (lane >> 4) * 4 + reg;
        int gcol = nb0 + wn * 32 + f * 16 + (lane & 15);
        int which = gcol >> 7, c = gcol & 127;
        short* dst = which ? v2b : k2b;
        dst[(size_t)grow * 128 + c] = f2b(acc[f][reg]);
      }
    }
  } else {
    // ---- qh GEMM: M=64 tile ----
    const int qid = blockIdx.x - NKV;
    const int b = qid >> 9;
    const int n0 = (qid & 511) * 64;
    const int xq = n0 >> 10, yq0 = (n0 >> 5) & 31;
    const float2* tabX = tabs;
    const float2* tabY = tabs + 2048;
    const float2* tabZ = tabs + 4096;
    f32x4 acc[4][2];
#pragma unroll
    for (int m = 0; m < 4; m++)
#pragma unroll
      for (int f = 0; f < 2; f++) acc[m][f] = (f32x4){0.f, 0.f, 0.f, 0.f};

    for (int ct = 0; ct < 5; ct++) {
      __syncthreads();
      {
#pragma unroll
        for (int it = 0; it < 2; it++) {
          int u = it * 256 + t;
          int r = u >> 3, g = u & 7;
          if (ct < 3) {
            int n = n0 + r;
            int x = n >> 10, y = (n >> 5) & 31, z = n & 31;
            int cell = (ct == 0) ? (z * 32 + x) : (ct == 1) ? (y * 32 + x) : (z * 32 + y);
            const int4 src = *reinterpret_cast<const int4*>(
                tri_tb + ((size_t)(b * 3 + ct) * 1024 + cell) * 64 + g * 8);
            *reinterpret_cast<int4*>(&A_lds[(r * 8 + (g ^ (r & 7))) * 8]) = src;
          } else {
            int i0 = (ct - 3) * 32 + g * 4;
            int z = r & 31, y = yq0 + (r >> 5);
            bf16x8v v;
#pragma unroll
            for (int q = 0; q < 4; q++) {
              int i = i0 + q;
              float2 exy = cmul(tabX[xq * 64 + i], tabY[y * 64 + i]);
              float2 e = cmul(exy, tabZ[z * 64 + i]);
              v[q * 2]     = f2b(e.y);
              v[q * 2 + 1] = f2b(e.x);
            }
            *reinterpret_cast<bf16x8v*>(&A_lds[(r * 8 + (g ^ (r & 7))) * 8]) = v;
          }
        }
      }
      {
#pragma unroll
        for (int it = 0; it < 4; it++) {
          int u = it * 256 + t;
          int col = u >> 3, g = u & 7;
          const int4 src = *reinterpret_cast<const int4*>(
              Wqb_s + (size_t)col * 320 + ct * 64 + g * 8);
          *reinterpret_cast<int4*>(&B_lds[(col * 8 + (g ^ (col & 7))) * 8]) = src;
        }
      }
      __syncthreads();
#pragma unroll
      for (int ks = 0; ks < 2; ks++) {
        int kb = ks * 4 + (lane >> 4);
        bf16x8v a[4], bb[2];
#pragma unroll
        for (int m = 0; m < 4; m++) {
          int row = m * 16 + (lane & 15);
          a[m] = *reinterpret_cast<const bf16x8v*>(&A_lds[(row * 8 + (kb ^ (row & 7))) * 8]);
        }
#pragma unroll
        for (int f = 0; f < 2; f++) {
          int col = w * 32 + f * 16 + (lane & 15);
          bb[f] = *reinterpret_cast<const bf16x8v*>(&B_lds[(col * 8 + (kb ^ (col & 7))) * 8]);
        }
#pragma unroll
        for (int m = 0; m < 4; m++)
#pragma unroll
          for (int f = 0; f < 2; f++)
            acc[m][f] = __builtin_amdgcn_mfma_f32_16x16x32_bf16(a[m], bb[f], acc[m][f], 0, 0, 0);
      }
    }
#pragma unroll
    for (int m = 0; m < 4; m++)
#pragma unroll
      for (int f = 0; f < 2; f++)
#pragma unroll
        for (int reg = 0; reg < 4; reg++) {
          int row = m * 16 + (lane >> 4) * 4 + reg;
          int col = w * 32 + f * 16 + (lane & 15);
          qh_g[((size_t)b * NVOX + n0 + row) * 128 + col] = f2b(acc[m][f][reg] + qcb[col]);
        }
  }
}

// ---------- attention + fused xy-plane reduction ----------
__global__ __launch_bounds__(256) void k_attn(
    const short* __restrict__ qh_g, const short* __restrict__ k2b,
    const short* __restrict__ v2b, const float* __restrict__ proj,
    bf16* __restrict__ obuf, float* __restrict__ pacc) {
  __shared__ __align__(16) ushort sIr[160][4];
  __shared__ __align__(16) float sW4[160][4];
  __shared__ __align__(16) float lg[160 * 8];
  __shared__ __align__(16) short o_lds[32][128];
  __shared__ float sxy[2][128];
  const int b = blockIdx.y;
  const int n0 = blockIdx.x * 32;
  const int t = threadIdx.x;

  // phase C: projection + bilinear taps (t < 160)
  if (t < 160) {
    int r = t / J5, j = t % J5;
    int n = n0 + r;
    int x = n >> 10, y = (n >> 5) & 31, z = n & 31;
    const float SC = (float)(1.0 + 0.1 + 1e-05);
    float fx = ((float)x / 31.0f - 0.5f) * 2.0f * SC;
    float fy = ((float)y / 31.0f - 0.5f) * 2.0f * SC;
    float fz = ((float)z / 31.0f - 0.5f) * 2.0f * SC;
    const float* P = proj + (size_t)(b * J5 + j) * 16;
    float pc0 = fmaf(fx, P[0], fmaf(fy, P[1], fmaf(fz, P[2],  P[3])));
    float pc1 = fmaf(fx, P[4], fmaf(fy, P[5], fmaf(fz, P[6],  P[7])));
    float pc2 = fmaf(fx, P[8], fmaf(fy, P[9], fmaf(fz, P[10], P[11])));
    float px = pc0 / pc2, py = pc1 / pc2;
    float gx = fminf(fmaxf((px / 223.0f - 0.5f) * 2.0f, -1.0f), 1.0f);
    float gy = fminf(fmaxf((py / 223.0f - 0.5f) * 2.0f, -1.0f), 1.0f);
    float ux = (gx + 1.0f) * 0.5f * 15.0f;
    float uy = (gy + 1.0f) * 0.5f * 15.0f;
    float fx0 = floorf(ux), fy0 = floorf(uy);
    int x0 = (int)fx0, y0 = (int)fy0;
    float wx = ux - fx0, wy = uy - fy0;
    int x1 = min(x0 + 1, 15), y1 = min(y0 + 1, 15);
    x0 = min(max(x0, 0), 15); y0 = min(max(y0, 0), 15);
    int rowb = (b * J5 + j) * 256;
    sIr[t][0] = (ushort)(rowb + y0 * 16 + x0);
    sIr[t][1] = (ushort)(rowb + y0 * 16 + x1);
    sIr[t][2] = (ushort)(rowb + y1 * 16 + x0);
    sIr[t][3] = (ushort)(rowb + y1 * 16 + x1);
    sW4[t][0] = (1.f - wx) * (1.f - wy);
    sW4[t][1] = wx * (1.f - wy);
    sW4[t][2] = (1.f - wx) * wy;
    sW4[t][3] = wx * wy;
  }
  __syncthreads();

  // phase D: logits
  {
    const int oct = t & 15, rjIdx = t >> 4;
    const int c0 = oct * 8;
#pragma unroll
    for (int it = 0; it < 10; it++) {
      int rj = rjIdx + it * 16;
      int r = rj / J5;
      ushort4 I4 = *reinterpret_cast<const ushort4*>(sIr[rj]);
      float4 W4 = *reinterpret_cast<const float4*>(sW4[rj]);
      bf16x8v t0 = *reinterpret_cast<const bf16x8v*>(k2b + (size_t)I4.x * 128 + c0);
      bf16x8v t1 = *reinterpret_cast<const bf16x8v*>(k2b + (size_t)I4.y * 128 + c0);
      bf16x8v t2 = *reinterpret_cast<const bf16x8v*>(k2b + (size_t)I4.z * 128 + c0);
      bf16x8v t3 = *reinterpret_cast<const bf16x8v*>(k2b + (size_t)I4.w * 128 + c0);
      bf16x8v q8 = *reinterpret_cast<const bf16x8v*>(qh_g + ((size_t)b * NVOX + n0 + r) * 128 + c0);
      float pv = 0.f;
#pragma unroll
      for (int e = 0; e < 8; e++) {
        float kh = fmaf(W4.x, b2f(t0[e]), fmaf(W4.y, b2f(t1[e]),
                   fmaf(W4.z, b2f(t2[e]), W4.w * b2f(t3[e]))));
        pv = fmaf(b2f(q8[e]), kh, pv);
      }
      pv += __shfl_xor(pv, 1);
      if (!(oct & 1)) lg[rj * 8 + (oct >> 1)] = pv * 0.25f;
    }
  }
  __syncthreads();

  // phase E: softmax
  {
    int r = t >> 3, h = t & 7;
    float l[J5];
    float m = -1e30f;
#pragma unroll
    for (int j = 0; j < J5; j++) { l[j] = lg[(r * J5 + j) * 8 + h]; m = fmaxf(m, l[j]); }
    float sden = 0.f;
#pragma unroll
    for (int j = 0; j < J5; j++) { l[j] = expf(l[j] - m); sden += l[j]; }
    float inv = 1.0f / sden;
#pragma unroll
    for (int j = 0; j < J5; j++) lg[(r * J5 + j) * 8 + h] = l[j] * inv;
  }
  __syncthreads();

  // phase F: output + stash bf16 rows in LDS for xy reduction
  {
    const int oct = t & 15;
    const int c0 = oct * 8;
#pragma unroll
    for (int it = 0; it < 2; it++) {
      int r = (t >> 4) + it * 16;
      float o8[8] = {0.f, 0.f, 0.f, 0.f, 0.f, 0.f, 0.f, 0.f};
#pragma unroll
      for (int j = 0; j < J5; j++) {
        int rj = r * J5 + j;
        float aw = lg[rj * 8 + (oct >> 1)];
        ushort4 I4 = *reinterpret_cast<const ushort4*>(sIr[rj]);
        float4 W4 = *reinterpret_cast<const float4*>(sW4[rj]);
        float w0 = aw * W4.x, w1 = aw * W4.y, w2 = aw * W4.z, w3 = aw * W4.w;
        bf16x8v t0 = *reinterpret_cast<const bf16x8v*>(v2b + (size_t)I4.x * 128 + c0);
        bf16x8v t1 = *reinterpret_cast<const bf16x8v*>(v2b + (size_t)I4.y * 128 + c0);
        bf16x8v t2 = *reinterpret_cast<const bf16x8v*>(v2b + (size_t)I4.z * 128 + c0);
        bf16x8v t3 = *reinterpret_cast<const bf16x8v*>(v2b + (size_t)I4.w * 128 + c0);
#pragma unroll
        for (int e = 0; e < 8; e++) {
          o8[e] = fmaf(w0, b2f(t0[e]), o8[e]);
          o8[e] = fmaf(w1, b2f(t1[e]), o8[e]);
          o8[e] = fmaf(w2, b2f(t2[e]), o8[e]);
          o8[e] = fmaf(w3, b2f(t3[e]), o8[e]);
        }
      }
      bf16x8v out;
#pragma unroll
      for (int e = 0; e < 8; e++) out[e] = f2b(o8[e]);
      *reinterpret_cast<bf16x8v*>((short*)obuf + ((size_t)b * NVOX + n0 + r) * 128 + c0) = out;
      *reinterpret_cast<bf16x8v*>(&o_lds[r][c0]) = out;
    }
  }
  __syncthreads();

  // xy-plane row (sum over z, complete within block): pacc[(b*96+32+y)*32+x]
  {
    int c = t & 127, half = t >> 7;
    float s = 0.f;
#pragma unroll
    for (int i = 0; i < 16; i++) s += b2f(o_lds[half * 16 + i][c]);
    sxy[half][c] = s;
  }
  __syncthreads();
  if (t < 128) {
    int x = n0 >> 10, y = (n0 >> 5) & 31;
    pacc[((size_t)(b * 96 + 32 + y) * 32 + x) * 128 + t] = sxy[0][t] + sxy[1][t];
  }
}

// ---------- xz + yz plane reductions ----------
__global__ __launch_bounds__(128) void k_reduce(const bf16* __restrict__ obuf,
                                                float* __restrict__ pacc) {
  int blk = blockIdx.x;          // 0..255 ; 8 cells/block
  int b = blockIdx.y;
  int t = threadIdx.x;
  int oct = t & 15, sub = t >> 4;
  int c0 = oct * 8;
  int cell = blk * 8 + sub;      // 0..2047
  const short* ob = (const short*)obuf + (size_t)b * NVOX * 128;
  float a8[8] = {0.f, 0.f, 0.f, 0.f, 0.f, 0.f, 0.f, 0.f};
  size_t prow;
  if (cell < 1024) {             // xz: row=z, col=x ; sum over y
    int z = cell >> 5, x = cell & 31;
    for (int y = 0; y < 32; y++) {
      bf16x8v u = *reinterpret_cast<const bf16x8v*>(ob + ((size_t)(x * 1024 + y * 32 + z) * 128 + c0));
#pragma unroll
      for (int e = 0; e < 8; e++) a8[e] += b2f(u[e]);
    }
    prow = ((size_t)(b * 96 + z) * 32 + x) * 128 + c0;
  } else {                       // yz: row=z, col=y ; sum over x
    int e2 = cell - 1024;
    int z = e2 >> 5, y = e2 & 31;
    for (int x = 0; x < 32; x++) {
      bf16x8v u = *reinterpret_cast<const bf16x8v*>(ob + ((size_t)(x * 1024 + y * 32 + z) * 128 + c0));
#pragma unroll
      for (int e = 0; e < 8; e++) a8[e] += b2f(u[e]);
    }
    prow = ((size_t)(b * 96 + 64 + z) * 32 + y) * 128 + c0;
  }
  *(float4*)(&pacc[prow])     = (float4){a8[0], a8[1], a8[2], a8[3]};
  *(float4*)(&pacc[prow + 4]) = (float4){a8[4], a8[5], a8[6], a8[7]};
}

// ---------- final projection ----------
__global__ __launch_bounds__(128) void k_final(
    const float* __restrict__ pacc, const float* __restrict__ Wo,
    const float* __restrict__ obb, float* __restrict__ outp) {
  int bp = blockIdx.x;
  int b = bp / 96, prow = bp % 96;
  int obase = blockIdx.y * 16;
  __shared__ __align__(16) float lds[32 * 129];
  for (int idx = threadIdx.x; idx < 4096; idx += 128) {
    int col = idx >> 7, k = idx & 127;
    lds[col * 129 + k] = pacc[(size_t)bp * 32 * 128 + idx] * (1.0f / 32.0f);
  }
  __syncthreads();
  for (int e = threadIdx.x; e < 16 * 32; e += 128) {
    int o = obase + (e >> 5), col = e & 31;
    float val = obb[o];
    const float* wr = Wo + (size_t)o * 128;
    const float* lr = lds + col * 129;
    for (int k = 0; k < 128; k++) val = fmaf(wr[k], lr[k], val);
    outp[((size_t)(b * 64 + o) * 96 + prow) * 32 + col] = val;
  }
}

extern "C" void kernel_launch(void* const* d_in, const int* in_sizes, int n_in,
                              void* d_out, int out_size, void* d_ws, size_t ws_size,
                              hipStream_t stream) {
  const float* tp     = (const float*)d_in[0];
  const float* img    = (const float*)d_in[1];
  const float* proj   = (const float*)d_in[2];
  const float* k_w    = (const float*)d_in[4];
  const float* k_b    = (const float*)d_in[5];
  const float* q_w    = (const float*)d_in[6];
  const float* q_b    = (const float*)d_in[7];
  const float* v_w    = (const float*)d_in[8];
  const float* v_b    = (const float*)d_in[9];
  const float* in_w   = (const float*)d_in[10];
  const float* in_b   = (const float*)d_in[11];
  const float* out_w  = (const float*)d_in[12];
  const float* out_b  = (const float*)d_in[13];
  const float* proj_w = (const float*)d_in[14];
  const float* proj_b = (const float*)d_in[15];
  const int B = 2;

  float* ws = (float*)d_ws;
  size_t off = 0;
  short*  tri_tb = (short*)(ws + off);  off += 196608;   // 2*3*1024*64 bf16
  short*  Wkvb2  = (short*)(ws + off);  off += 188416;   // 256*1472 bf16
  short*  Wqb_s  = (short*)(ws + off);  off += 20480;    // 128*320 bf16
  short*  pe_tab = (short*)(ws + off);  off += 16384;    // 256*128 bf16
  float2* tabs   = (float2*)(ws + off); off += 12288;    // 3*32*64 cplx
  float*  qcb    = ws + off;            off += 128;
  float*  Wo     = ws + off;            off += 8192;
  float*  obb    = ws + off;            off += 64;
  short*  k2b    = (short*)(ws + off);  off += 163840;   // 2560*128 bf16
  short*  v2b    = (short*)(ws + off);  off += 163840;
  float*  pacc   = ws + off;            off += 786432;   // 2*96*32*128
  short*  qh_g   = (short*)(ws + off);  off += 4194304;  // 2*32768*128 bf16
  bf16*   obuf   = (bf16*)(ws + off);   off += 2097152;  // 2*32768*128 bf16
  if (ws_size < off * sizeof(float)) return;  // ~31.4 MB; clean fail if short

  k_prep<<<dim3(NB_TOTAL), dim3(256), 0, stream>>>(
      tp, k_w, k_b, q_w, q_b, v_w, v_b, in_w, in_b, out_w, out_b, proj_w, proj_b,
      tabs, Wqb_s, Wo, qcb, obb, tri_tb, Wkvb2, pe_tab);
  k_qkv<<<dim3(NKV + NVOX / 64 * B), dim3(256), 0, stream>>>(
      img, Wkvb2, pe_tab, k2b, v2b, tri_tb, Wqb_s, qcb, tabs, qh_g);
  k_attn<<<dim3(NVOX / 32, B), dim3(256), 0, stream>>>(qh_g, k2b, v2b, proj, obuf, pacc);
  k_reduce<<<dim3(256, B), dim3(128), 0, stream>>>(obuf, pacc);
  k_final<<<dim3(B * 96, 4), dim3(128), 0, stream>>>(pacc, Wo, obb, (float*)d_out);
}

// Round 10
// 94.858 us; speedup vs baseline: 1.2681x; 1.0072x over previous
//
#include <hip/hip_runtime.h>
#include <hip/hip_bf16.h>
#include <cstddef>

#define NVOX 32768
#define J5 5
#define KB2 1472           // folded K for kv GEMM: 1280 img | 128 pe | 64 const
typedef __attribute__((ext_vector_type(8))) short s16x8;
typedef __attribute__((ext_vector_type(8))) _Float16 f16x8;
typedef __attribute__((ext_vector_type(2))) _Float16 h2t;
typedef __attribute__((ext_vector_type(4))) float f32x4;

static __device__ __forceinline__ float pe_val(int pos, int c) {
  float dv = expf((float)(c & ~1) * (-0.0719557841560639f));
  float arg = (float)pos * dv;
  return (c & 1) ? cosf(arg) : sinf(arg);
}
static __device__ __forceinline__ short f2h(float f) {
  _Float16 h = (_Float16)f;
  return *reinterpret_cast<short*>(&h);
}
static __device__ __forceinline__ float h2f(short s) {
  _Float16 h = *reinterpret_cast<_Float16*>(&s);
  return (float)h;
}
static __device__ __forceinline__ float2 cmul(float2 a, float2 b) {
  return make_float2(a.x * b.x - a.y * b.y, a.x * b.y + a.y * b.x);
}
// 8-wide f16 dot with f32 accumulate (fdot2 if available)
static __device__ __forceinline__ float dot8h(f16x8 a, f16x8 b, float acc) {
#if __has_builtin(__builtin_amdgcn_fdot2)
#pragma unroll
  for (int i = 0; i < 4; i++) {
    h2t x; x[0] = a[2 * i]; x[1] = a[2 * i + 1];
    h2t y; y[0] = b[2 * i]; y[1] = b[2 * i + 1];
    acc = __builtin_amdgcn_fdot2(x, y, acc, false);
  }
#else
#pragma unroll
  for (int i = 0; i < 8; i++) acc = fmaf((float)a[i], (float)b[i], acc);
#endif
  return acc;
}

// block-range boundaries for k_prep sections
#define NB_TABS   24
#define NB_WQPE   64
#define NB_WQC    96
#define NB_WO     32
#define NB_QCB    1
#define NB_TRI2   96
#define NB_FOLDW  1280
#define NB_PETAB  128
#define NB_WIN    128
#define NB_CB     1
#define B_TABS   0
#define B_WQPE   (B_TABS + NB_TABS)
#define B_WQC    (B_WQPE + NB_WQPE)
#define B_WO     (B_WQC + NB_WQC)
#define B_QCB    (B_WO + NB_WO)
#define B_TRI2   (B_QCB + NB_QCB)
#define B_FOLDW  (B_TRI2 + NB_TRI2)
#define B_PETAB  (B_FOLDW + NB_FOLDW)
#define B_WIN    (B_PETAB + NB_PETAB)
#define B_CB     (B_WIN + NB_WIN)
#define NB_TOTAL (B_CB + NB_CB)   // 1850

// ---------- one merged prep kernel (all outputs f16 bits in short buffers) ----------
__global__ __launch_bounds__(256) void k_prep(
    const float* __restrict__ tp,
    const float* __restrict__ k_w, const float* __restrict__ k_b,
    const float* __restrict__ q_w, const float* __restrict__ q_b,
    const float* __restrict__ v_w, const float* __restrict__ v_b,
    const float* __restrict__ in_w, const float* __restrict__ in_b,
    const float* __restrict__ out_w, const float* __restrict__ out_b,
    const float* __restrict__ proj_w, const float* __restrict__ proj_b,
    float2* __restrict__ tabs, short* __restrict__ Wqb_s, float* __restrict__ Wo,
    float* __restrict__ qcb, float* __restrict__ obb,
    short* __restrict__ tri_tb, short* __restrict__ Wkvb2, short* __restrict__ pe_tab) {
  __shared__ short tile_s[64][65];
  const int bx = blockIdx.x, t = threadIdx.x;

  if (bx < B_WQPE) {
    int idx = bx * 256 + t;
    if (idx < 6144) {
      int tb = idx >> 11, rem = idx & 2047;
      int pos = rem >> 6, i = rem & 63;
      float dv = expf((float)(2 * i) * (-0.0719557841560639f));
      float mult = (tb == 0) ? 1024.0f : (tb == 1) ? 32.0f : 1.0f;
      float ang = (float)pos * mult * dv;
      tabs[idx] = make_float2(cosf(ang), sinf(ang));
    }
  } else if (bx < B_WQC) {
    int e = (bx - B_WQPE) * 256 + t;
    int c = e >> 7, j = e & 127;
    Wqb_s[(size_t)c * 320 + 192 + j] = f2h(in_w[(size_t)c * 128 + j]);
  } else if (bx < B_WO) {
    int e = (bx - B_WQC) * 256 + t;
    int c = e / 192, k = e % 192;
    const float* ir = in_w + (size_t)c * 128;
    float acc = 0.f;
    for (int j = 0; j < 128; j++) acc = fmaf(ir[j], q_w[(size_t)j * 192 + k], acc);
    Wqb_s[(size_t)c * 320 + k] = f2h(acc);
  } else if (bx < B_QCB) {
    int e = (bx - B_WO) * 256 + t;
    int o = e >> 7, c = e & 127;
    const float* pr = proj_w + (size_t)o * 128;
    float acc = 0.f;
    for (int j = 0; j < 128; j++) acc = fmaf(pr[j], out_w[(size_t)j * 128 + c], acc);
    Wo[e] = acc;
  } else if (bx < B_TRI2) {
    if (t < 128) {
      float acc = in_b[t];
      const float* ir = in_w + (size_t)t * 128;
      for (int j = 0; j < 128; j++) acc = fmaf(ir[j], q_b[j], acc);
      qcb[t] = acc;
    }
    if (t < 64) {
      float acc = proj_b[t];
      const float* pr = proj_w + (size_t)t * 128;
      for (int j = 0; j < 128; j++) acc = fmaf(pr[j], out_b[j], acc);
      obb[t] = acc;
    }
  } else if (bx < B_FOLDW) {
    // LDS-tiled tri transpose (f16)
    int b3 = bx - B_TRI2;
    int segb = b3 >> 4, tile = b3 & 15;
    int b = segb / 3, seg = segb % 3;
    int cc = t >> 2, q = t & 3;
#pragma unroll
    for (int di = 0; di < 2; di++) {
      int i = tile * 2 + di;
      const float* src = tp + (((size_t)(b * 64 + cc)) * 96 + seg * 32 + i) * 32 + q * 8;
      float4 a0 = *(const float4*)src;
      float4 a1 = *(const float4*)(src + 4);
      short* dst = &tile_s[cc][di * 32 + q * 8];
      dst[0] = f2h(a0.x); dst[1] = f2h(a0.y); dst[2] = f2h(a0.z); dst[3] = f2h(a0.w);
      dst[4] = f2h(a1.x); dst[5] = f2h(a1.y); dst[6] = f2h(a1.z); dst[7] = f2h(a1.w);
    }
    __syncthreads();
    int cp = t >> 2;
    int cc0 = q * 16;
    s16x8 v0, v1;
#pragma unroll
    for (int e = 0; e < 8; e++) { v0[e] = tile_s[cc0 + e][cp]; v1[e] = tile_s[cc0 + 8 + e][cp]; }
    short* outp = tri_tb + (((size_t)(b * 3 + seg) * 1024) + tile * 64 + cp) * 64 + cc0;
    *reinterpret_cast<s16x8*>(outp) = v0;
    *reinterpret_cast<s16x8*>(outp + 8) = v1;
  } else if (bx < B_PETAB) {
    int u = (bx - B_FOLDW) * 256 + t;
    int c = u / 1280, k = u % 1280;
    const float* w = (c < 128) ? k_w : v_w;
    const float* ir = in_w + (size_t)(128 + c) * 128;
    float acc = 0.f;
    for (int j = 0; j < 128; j++) acc = fmaf(ir[j], w[(size_t)j * 1280 + k], acc);
    Wkvb2[(size_t)c * KB2 + k] = f2h(acc);
  } else if (bx < B_WIN) {
    int e = (bx - B_PETAB) * 256 + t;
    int p = e >> 7, c = e & 127;
    pe_tab[e] = f2h(pe_val(p, c));
  } else if (bx < B_CB) {
    int e = (bx - B_WIN) * 256 + t;
    int c = e >> 7, j = e & 127;
    Wkvb2[(size_t)c * KB2 + 1280 + j] = f2h(in_w[(size_t)(128 + c) * 128 + j]);
  } else {
    int c = t;
    int which = c >> 7;
    const float* bias = which ? v_b : k_b;
    const float* ir = in_w + (size_t)(128 + c) * 128;
    float acc = in_b[128 + c];
    for (int j = 0; j < 128; j++) acc = fmaf(bias[j], ir[j], acc);
    short* row = Wkvb2 + (size_t)c * KB2 + 1408;
    row[0] = f2h(acc);
    for (int k = 1; k < 64; k++) row[k] = 0;
  }
}

// ---------- merged GEMMs (f16 MFMA): blocks [0,320) = kv ; [320,1344) = qh ----------
#define NKV 320
__global__ __launch_bounds__(256) void k_qkv(
    const float* __restrict__ img, const short* __restrict__ Wkvb2,
    const short* __restrict__ pe_tab, short* __restrict__ k2b, short* __restrict__ v2b,
    const short* __restrict__ tri_tb, const short* __restrict__ Wqb_s,
    const float* __restrict__ qcb, const float2* __restrict__ tabs,
    short* __restrict__ qh_g) {
  __shared__ __align__(16) short A_lds[64 * 64];
  __shared__ __align__(16) short B_lds[128 * 64];
  const int t = threadIdx.x;
  const int lane = t & 63, w = t >> 6;

  if (blockIdx.x < NKV) {
    const int kvid = blockIdx.x;
    const int m0 = (kvid >> 2) * 32;
    const int nb0 = (kvid & 3) * 64;
    const int wm = w & 1, wn = w >> 1;
    f32x4 acc[2];
    acc[0] = (f32x4){0.f, 0.f, 0.f, 0.f};
    acc[1] = (f32x4){0.f, 0.f, 0.f, 0.f};
    for (int ct = 0; ct < 23; ct++) {
      __syncthreads();
      {
        int r = t >> 3, g = t & 7;
        s16x8 v;
        if (ct < 20) {
          int row = m0 + r;
          int bj = row >> 8, p = row & 255;
          const float* src = img + ((size_t)(bj * 257 + 1 + p)) * 1280 + ct * 64 + g * 8;
          float4 a0 = *(const float4*)src;
          float4 a1 = *(const float4*)(src + 4);
          v[0] = f2h(a0.x); v[1] = f2h(a0.y); v[2] = f2h(a0.z); v[3] = f2h(a0.w);
          v[4] = f2h(a1.x); v[5] = f2h(a1.y); v[6] = f2h(a1.z); v[7] = f2h(a1.w);
        } else if (ct < 22) {
          int p = (m0 + r) & 255;
          v = *reinterpret_cast<const s16x8*>(pe_tab + (size_t)p * 128 + (ct - 20) * 64 + g * 8);
        } else {
          v = (s16x8){0, 0, 0, 0, 0, 0, 0, 0};
          if (g == 0) v[0] = (short)0x3C00;   // f16 1.0 at k-offset 1408
        }
        *reinterpret_cast<s16x8*>(&A_lds[(r * 8 + (g ^ (r & 7))) * 8]) = v;
      }
      {
#pragma unroll
        for (int it = 0; it < 2; it++) {
          int u = it * 256 + t;
          int r2 = u >> 3, g = u & 7;
          const int4 src = *reinterpret_cast<const int4*>(
              Wkvb2 + (size_t)((kvid & 3) * 64 + r2) * KB2 + ct * 64 + g * 8);
          *reinterpret_cast<int4*>(&B_lds[(r2 * 8 + (g ^ (r2 & 7))) * 8]) = src;
        }
      }
      __syncthreads();
#pragma unroll
      for (int ks = 0; ks < 2; ks++) {
        int kb = ks * 4 + (lane >> 4);
        int arow = wm * 16 + (lane & 15);
        f16x8 a = *reinterpret_cast<const f16x8*>(&A_lds[(arow * 8 + (kb ^ (arow & 7))) * 8]);
#pragma unroll
        for (int f = 0; f < 2; f++) {
          int bcol = wn * 32 + f * 16 + (lane & 15);
          f16x8 bb = *reinterpret_cast<const f16x8*>(&B_lds[(bcol * 8 + (kb ^ (bcol & 7))) * 8]);
          acc[f] = __builtin_amdgcn_mfma_f32_16x16x32_f16(a, bb, acc[f], 0, 0, 0);
        }
      }
    }
#pragma unroll
    for (int f = 0; f < 2; f++) {
#pragma unroll
      for (int reg = 0; reg < 4; reg++) {
        int grow = m0 + wm * 16 + (lane >> 4) * 4 + reg;
        int gcol = nb0 + wn * 32 + f * 16 + (lane & 15);
        int which = gcol >> 7, c = gcol & 127;
        short* dst = which ? v2b : k2b;
        dst[(size_t)grow * 128 + c] = f2h(acc[f][reg]);
      }
    }
  } else {
    const int qid = blockIdx.x - NKV;
    const int b = qid >> 9;
    const int n0 = (qid & 511) * 64;
    const int xq = n0 >> 10, yq0 = (n0 >> 5) & 31;
    const float2* tabX = tabs;
    const float2* tabY = tabs + 2048;
    const float2* tabZ = tabs + 4096;
    f32x4 acc[4][2];
#pragma unroll
    for (int m = 0; m < 4; m++)
#pragma unroll
      for (int f = 0; f < 2; f++) acc[m][f] = (f32x4){0.f, 0.f, 0.f, 0.f};

    for (int ct = 0; ct < 5; ct++) {
      __syncthreads();
      {
#pragma unroll
        for (int it = 0; it < 2; it++) {
          int u = it * 256 + t;
          int r = u >> 3, g = u & 7;
          if (ct < 3) {
            int n = n0 + r;
            int x = n >> 10, y = (n >> 5) & 31, z = n & 31;
            int cell = (ct == 0) ? (z * 32 + x) : (ct == 1) ? (y * 32 + x) : (z * 32 + y);
            const int4 src = *reinterpret_cast<const int4*>(
                tri_tb + ((size_t)(b * 3 + ct) * 1024 + cell) * 64 + g * 8);
            *reinterpret_cast<int4*>(&A_lds[(r * 8 + (g ^ (r & 7))) * 8]) = src;
          } else {
            int i0 = (ct - 3) * 32 + g * 4;
            int z = r & 31, y = yq0 + (r >> 5);
            s16x8 v;
#pragma unroll
            for (int q = 0; q < 4; q++) {
              int i = i0 + q;
              float2 exy = cmul(tabX[xq * 64 + i], tabY[y * 64 + i]);
              float2 e = cmul(exy, tabZ[z * 64 + i]);
              v[q * 2]     = f2h(e.y);
              v[q * 2 + 1] = f2h(e.x);
            }
            *reinterpret_cast<s16x8*>(&A_lds[(r * 8 + (g ^ (r & 7))) * 8]) = v;
          }
        }
      }
      {
#pragma unroll
        for (int it = 0; it < 4; it++) {
          int u = it * 256 + t;
          int col = u >> 3, g = u & 7;
          const int4 src = *reinterpret_cast<const int4*>(
              Wqb_s + (size_t)col * 320 + ct * 64 + g * 8);
          *reinterpret_cast<int4*>(&B_lds[(col * 8 + (g ^ (col & 7))) * 8]) = src;
        }
      }
      __syncthreads();
#pragma unroll
      for (int ks = 0; ks < 2; ks++) {
        int kb = ks * 4 + (lane >> 4);
        f16x8 a[4], bb[2];
#pragma unroll
        for (int m = 0; m < 4; m++) {
          int row = m * 16 + (lane & 15);
          a[m] = *reinterpret_cast<const f16x8*>(&A_lds[(row * 8 + (kb ^ (row & 7))) * 8]);
        }
#pragma unroll
        for (int f = 0; f < 2; f++) {
          int col = w * 32 + f * 16 + (lane & 15);
          bb[f] = *reinterpret_cast<const f16x8*>(&B_lds[(col * 8 + (kb ^ (col & 7))) * 8]);
        }
#pragma unroll
        for (int m = 0; m < 4; m++)
#pragma unroll
          for (int f = 0; f < 2; f++)
            acc[m][f] = __builtin_amdgcn_mfma_f32_16x16x32_f16(a[m], bb[f], acc[m][f], 0, 0, 0);
      }
    }
#pragma unroll
    for (int m = 0; m < 4; m++)
#pragma unroll
      for (int f = 0; f < 2; f++)
#pragma unroll
        for (int reg = 0; reg < 4; reg++) {
          int row = m * 16 + (lane >> 4) * 4 + reg;
          int col = w * 32 + f * 16 + (lane & 15);
          qh_g[((size_t)b * NVOX + n0 + row) * 128 + col] = f2h(acc[m][f][reg] + qcb[col]);
        }
  }
}

// ---------- attention + fused xy-plane reduction (f16 datapath) ----------
__global__ __launch_bounds__(256) void k_attn(
    const short* __restrict__ qh_g, const short* __restrict__ k2b,
    const short* __restrict__ v2b, const float* __restrict__ proj,
    short* __restrict__ obuf, float* __restrict__ pacc) {
  __shared__ __align__(16) ushort sIr[160][4];
  __shared__ __align__(16) float sW4[160][4];
  __shared__ __align__(16) float lg[160 * 8];
  __shared__ __align__(16) short o_lds[32][128];
  __shared__ float sxy[2][128];
  const int b = blockIdx.y;
  const int n0 = blockIdx.x * 32;
  const int t = threadIdx.x;

  // phase C: projection + bilinear taps (t < 160)
  if (t < 160) {
    int r = t / J5, j = t % J5;
    int n = n0 + r;
    int x = n >> 10, y = (n >> 5) & 31, z = n & 31;
    const float SC = (float)(1.0 + 0.1 + 1e-05);
    float fx = ((float)x / 31.0f - 0.5f) * 2.0f * SC;
    float fy = ((float)y / 31.0f - 0.5f) * 2.0f * SC;
    float fz = ((float)z / 31.0f - 0.5f) * 2.0f * SC;
    const float* P = proj + (size_t)(b * J5 + j) * 16;
    float pc0 = fmaf(fx, P[0], fmaf(fy, P[1], fmaf(fz, P[2],  P[3])));
    float pc1 = fmaf(fx, P[4], fmaf(fy, P[5], fmaf(fz, P[6],  P[7])));
    float pc2 = fmaf(fx, P[8], fmaf(fy, P[9], fmaf(fz, P[10], P[11])));
    float px = pc0 / pc2, py = pc1 / pc2;
    float gx = fminf(fmaxf((px / 223.0f - 0.5f) * 2.0f, -1.0f), 1.0f);
    float gy = fminf(fmaxf((py / 223.0f - 0.5f) * 2.0f, -1.0f), 1.0f);
    float ux = (gx + 1.0f) * 0.5f * 15.0f;
    float uy = (gy + 1.0f) * 0.5f * 15.0f;
    float fx0 = floorf(ux), fy0 = floorf(uy);
    int x0 = (int)fx0, y0 = (int)fy0;
    float wx = ux - fx0, wy = uy - fy0;
    int x1 = min(x0 + 1, 15), y1 = min(y0 + 1, 15);
    x0 = min(max(x0, 0), 15); y0 = min(max(y0, 0), 15);
    int rowb = (b * J5 + j) * 256;
    sIr[t][0] = (ushort)(rowb + y0 * 16 + x0);
    sIr[t][1] = (ushort)(rowb + y0 * 16 + x1);
    sIr[t][2] = (ushort)(rowb + y1 * 16 + x0);
    sIr[t][3] = (ushort)(rowb + y1 * 16 + x1);
    sW4[t][0] = (1.f - wx) * (1.f - wy);
    sW4[t][1] = wx * (1.f - wy);
    sW4[t][2] = (1.f - wx) * wy;
    sW4[t][3] = wx * wy;
  }
  __syncthreads();

  // phase D: logits — reordered: pv = Σ_tap w_t · dot(q, k_t), fdot2 per pair
  {
    const int oct = t & 15, rjIdx = t >> 4;
    const int c0 = oct * 8;
#pragma unroll
    for (int it = 0; it < 10; it++) {
      int rj = rjIdx + it * 16;
      int r = rj / J5;
      ushort4 I4 = *reinterpret_cast<const ushort4*>(sIr[rj]);
      float4 W4 = *reinterpret_cast<const float4*>(sW4[rj]);
      f16x8 t0 = *reinterpret_cast<const f16x8*>(k2b + (size_t)I4.x * 128 + c0);
      f16x8 t1 = *reinterpret_cast<const f16x8*>(k2b + (size_t)I4.y * 128 + c0);
      f16x8 t2 = *reinterpret_cast<const f16x8*>(k2b + (size_t)I4.z * 128 + c0);
      f16x8 t3 = *reinterpret_cast<const f16x8*>(k2b + (size_t)I4.w * 128 + c0);
      f16x8 q8 = *reinterpret_cast<const f16x8*>(qh_g + ((size_t)b * NVOX + n0 + r) * 128 + c0);
      float d0 = dot8h(q8, t0, 0.f);
      float d1 = dot8h(q8, t1, 0.f);
      float d2 = dot8h(q8, t2, 0.f);
      float d3 = dot8h(q8, t3, 0.f);
      float pv = fmaf(W4.x, d0, fmaf(W4.y, d1, fmaf(W4.z, d2, W4.w * d3)));
      pv += __shfl_xor(pv, 1);
      if (!(oct & 1)) lg[rj * 8 + (oct >> 1)] = pv * 0.25f;
    }
  }
  __syncthreads();

  // phase E: softmax
  {
    int r = t >> 3, h = t & 7;
    float l[J5];
    float m = -1e30f;
#pragma unroll
    for (int j = 0; j < J5; j++) { l[j] = lg[(r * J5 + j) * 8 + h]; m = fmaxf(m, l[j]); }
    float sden = 0.f;
#pragma unroll
    for (int j = 0; j < J5; j++) { l[j] = expf(l[j] - m); sden += l[j]; }
    float inv = 1.0f / sden;
#pragma unroll
    for (int j = 0; j < J5; j++) lg[(r * J5 + j) * 8 + h] = l[j] * inv;
  }
  __syncthreads();

  // phase F: output — mixed-precision FMA (f16 operand folds to v_fma_mix)
  {
    const int oct = t & 15;
    const int c0 = oct * 8;
#pragma unroll
    for (int it = 0; it < 2; it++) {
      int r = (t >> 4) + it * 16;
      float o8[8] = {0.f, 0.f, 0.f, 0.f, 0.f, 0.f, 0.f, 0.f};
#pragma unroll
      for (int j = 0; j < J5; j++) {
        int rj = r * J5 + j;
        float aw = lg[rj * 8 + (oct >> 1)];
        ushort4 I4 = *reinterpret_cast<const ushort4*>(sIr[rj]);
        float4 W4 = *reinterpret_cast<const float4*>(sW4[rj]);
        float w0 = aw * W4.x, w1 = aw * W4.y, w2 = aw * W4.z, w3 = aw * W4.w;
        f16x8 t0 = *reinterpret_cast<const f16x8*>(v2b + (size_t)I4.x * 128 + c0);
        f16x8 t1 = *reinterpret_cast<const f16x8*>(v2b + (size_t)I4.y * 128 + c0);
        f16x8 t2 = *reinterpret_cast<const f16x8*>(v2b + (size_t)I4.z * 128 + c0);
        f16x8 t3 = *reinterpret_cast<const f16x8*>(v2b + (size_t)I4.w * 128 + c0);
#pragma unroll
        for (int e = 0; e < 8; e++) {
          o8[e] = fmaf(w0, (float)t0[e], o8[e]);
          o8[e] = fmaf(w1, (float)t1[e], o8[e]);
          o8[e] = fmaf(w2, (float)t2[e], o8[e]);
          o8[e] = fmaf(w3, (float)t3[e], o8[e]);
        }
      }
      s16x8 out;
#pragma unroll
      for (int e = 0; e < 8; e++) out[e] = f2h(o8[e]);
      *reinterpret_cast<s16x8*>(obuf + ((size_t)b * NVOX + n0 + r) * 128 + c0) = out;
      *reinterpret_cast<s16x8*>(&o_lds[r][c0]) = out;
    }
  }
  __syncthreads();

  // xy-plane row (sum over z, complete within block)
  {
    int c = t & 127, half = t >> 7;
    float s = 0.f;
#pragma unroll
    for (int i = 0; i < 16; i++) s += h2f(o_lds[half * 16 + i][c]);
    sxy[half][c] = s;
  }
  __syncthreads();
  if (t < 128) {
    int x = n0 >> 10, y = (n0 >> 5) & 31;
    pacc[((size_t)(b * 96 + 32 + y) * 32 + x) * 128 + t] = sxy[0][t] + sxy[1][t];
  }
}

// ---------- xz + yz plane reductions ----------
__global__ __launch_bounds__(128) void k_reduce(const short* __restrict__ obuf,
                                                float* __restrict__ pacc) {
  int blk = blockIdx.x;
  int b = blockIdx.y;
  int t = threadIdx.x;
  int oct = t & 15, sub = t >> 4;
  int c0 = oct * 8;
  int cell = blk * 8 + sub;
  const short* ob = obuf + (size_t)b * NVOX * 128;
  float a8[8] = {0.f, 0.f, 0.f, 0.f, 0.f, 0.f, 0.f, 0.f};
  size_t prow;
  if (cell < 1024) {
    int z = cell >> 5, x = cell & 31;
    for (int y = 0; y < 32; y++) {
      f16x8 u = *reinterpret_cast<const f16x8*>(ob + ((size_t)(x * 1024 + y * 32 + z) * 128 + c0));
#pragma unroll
      for (int e = 0; e < 8; e++) a8[e] += (float)u[e];
    }
    prow = ((size_t)(b * 96 + z) * 32 + x) * 128 + c0;
  } else {
    int e2 = cell - 1024;
    int z = e2 >> 5, y = e2 & 31;
    for (int x = 0; x < 32; x++) {
      f16x8 u = *reinterpret_cast<const f16x8*>(ob + ((size_t)(x * 1024 + y * 32 + z) * 128 + c0));
#pragma unroll
      for (int e = 0; e < 8; e++) a8[e] += (float)u[e];
    }
    prow = ((size_t)(b * 96 + 64 + z) * 32 + y) * 128 + c0;
  }
  *(float4*)(&pacc[prow])     = (float4){a8[0], a8[1], a8[2], a8[3]};
  *(float4*)(&pacc[prow + 4]) = (float4){a8[4], a8[5], a8[6], a8[7]};
}

// ---------- final projection ----------
__global__ __launch_bounds__(128) void k_final(
    const float* __restrict__ pacc, const float* __restrict__ Wo,
    const float* __restrict__ obb, float* __restrict__ outp) {
  int bp = blockIdx.x;
  int b = bp / 96, prow = bp % 96;
  int obase = blockIdx.y * 16;
  __shared__ __align__(16) float lds[32 * 129];
  for (int idx = threadIdx.x; idx < 4096; idx += 128) {
    int col = idx >> 7, k = idx & 127;
    lds[col * 129 + k] = pacc[(size_t)bp * 32 * 128 + idx] * (1.0f / 32.0f);
  }
  __syncthreads();
  for (int e = threadIdx.x; e < 16 * 32; e += 128) {
    int o = obase + (e >> 5), col = e & 31;
    float val = obb[o];
    const float* wr = Wo + (size_t)o * 128;
    const float* lr = lds + col * 129;
    for (int k = 0; k < 128; k++) val = fmaf(wr[k], lr[k], val);
    outp[((size_t)(b * 64 + o) * 96 + prow) * 32 + col] = val;
  }
}

extern "C" void kernel_launch(void* const* d_in, const int* in_sizes, int n_in,
                              void* d_out, int out_size, void* d_ws, size_t ws_size,
                              hipStream_t stream) {
  const float* tp     = (const float*)d_in[0];
  const float* img    = (const float*)d_in[1];
  const float* proj   = (const float*)d_in[2];
  const float* k_w    = (const float*)d_in[4];
  const float* k_b    = (const float*)d_in[5];
  const float* q_w    = (const float*)d_in[6];
  const float* q_b    = (const float*)d_in[7];
  const float* v_w    = (const float*)d_in[8];
  const float* v_b    = (const float*)d_in[9];
  const float* in_w   = (const float*)d_in[10];
  const float* in_b   = (const float*)d_in[11];
  const float* out_w  = (const float*)d_in[12];
  const float* out_b  = (const float*)d_in[13];
  const float* proj_w = (const float*)d_in[14];
  const float* proj_b = (const float*)d_in[15];
  const int B = 2;

  float* ws = (float*)d_ws;
  size_t off = 0;
  short*  tri_tb = (short*)(ws + off);  off += 196608;   // 2*3*1024*64 f16
  short*  Wkvb2  = (short*)(ws + off);  off += 188416;   // 256*1472 f16
  short*  Wqb_s  = (short*)(ws + off);  off += 20480;    // 128*320 f16
  short*  pe_tab = (short*)(ws + off);  off += 16384;    // 256*128 f16
  float2* tabs   = (float2*)(ws + off); off += 12288;    // 3*32*64 cplx
  float*  qcb    = ws + off;            off += 128;
  float*  Wo     = ws + off;            off += 8192;
  float*  obb    = ws + off;            off += 64;
  short*  k2b    = (short*)(ws + off);  off += 163840;   // 2560*128 f16
  short*  v2b    = (short*)(ws + off);  off += 163840;
  float*  pacc   = ws + off;            off += 786432;   // 2*96*32*128
  short*  qh_g   = (short*)(ws + off);  off += 4194304;  // 2*32768*128 f16
  short*  obuf   = (short*)(ws + off);  off += 2097152;  // 2*32768*128 f16
  if (ws_size < off * sizeof(float)) return;  // ~31.4 MB; clean fail if short

  k_prep<<<dim3(NB_TOTAL), dim3(256), 0, stream>>>(
      tp, k_w, k_b, q_w, q_b, v_w, v_b, in_w, in_b, out_w, out_b, proj_w, proj_b,
      tabs, Wqb_s, Wo, qcb, obb, tri_tb, Wkvb2, pe_tab);
  k_qkv<<<dim3(NKV + NVOX / 64 * B), dim3(256), 0, stream>>>(
      img, Wkvb2, pe_tab, k2b, v2b, tri_tb, Wqb_s, qcb, tabs, qh_g);
  k_attn<<<dim3(NVOX / 32, B), dim3(256), 0, stream>>>(qh_g, k2b, v2b, proj, obuf, pacc);
  k_reduce<<<dim3(256, B), dim3(128), 0, stream>>>(obuf, pacc);
  k_final<<<dim3(B * 96, 4), dim3(128), 0, stream>>>(pacc, Wo, obb, (float*)d_out);
}